// Round 2
// baseline (2443.236 us; speedup 1.0000x reference)
//
#include <hip/hip_runtime.h>
#include <hip/hip_bf16.h>

// ---------------------------------------------------------------------------
// FactorizedAttentionBlock (TimeSformer divided space-time attention)
// DIM=768, NH=12, HD=64, HID=1152, B=8, T=8, HW=196, N=197, BT=64
// Device inputs/outputs are FP32. Internals: bf16 MFMA GEMMs, fp32 residual
// accumulated directly in d_out.
// ---------------------------------------------------------------------------

#define DIM   768
#define NH    12
#define HD    64
#define HID   1152
#define B_    8
#define T_    8
#define HW_   196
#define NTOK  197
#define BT_   64
#define MROWS (BT_ * NTOK)        // 12608 tokens (spatial)
#define TROWS (B_ * HW_ * T_)     // 12544 tokens (temporal)

typedef __bf16 bf16x8 __attribute__((ext_vector_type(8)));
typedef float  f32x4  __attribute__((ext_vector_type(4)));

__device__ inline float bf2f(ushort u) { return __uint_as_float(((unsigned)u) << 16); }
__device__ inline ushort f2bf(float f) {
    unsigned u = __float_as_uint(f);
    unsigned r = (u + 0x7fffu + ((u >> 16) & 1u)) >> 16;
    return (ushort)r;
}

__device__ inline float wred_sum(float v) {
    #pragma unroll
    for (int m = 32; m; m >>= 1) v += __shfl_xor(v, m);
    return v;
}
__device__ inline float wred_max(float v) {
    #pragma unroll
    for (int m = 32; m; m >>= 1) v = fmaxf(v, __shfl_xor(v, m));
    return v;
}

// ---------------------------------------------------------------------------
// fp32 -> bf16 cast (weights), fp32 copy (residual init)
// ---------------------------------------------------------------------------
__global__ __launch_bounds__(256) void cast_w(const float* __restrict__ in, ushort* __restrict__ out, int n8)
{
    int i = blockIdx.x * 256 + threadIdx.x;
    if (i >= n8) return;
    float4 a = *(const float4*)(in + (size_t)i * 8);
    float4 b = *(const float4*)(in + (size_t)i * 8 + 4);
    ushort o[8] = {f2bf(a.x), f2bf(a.y), f2bf(a.z), f2bf(a.w),
                   f2bf(b.x), f2bf(b.y), f2bf(b.z), f2bf(b.w)};
    *(uint4*)(out + (size_t)i * 8) = *(const uint4*)o;
}

__global__ __launch_bounds__(256) void copy_f32(const float* __restrict__ in, float* __restrict__ out, int n4)
{
    int i = blockIdx.x * 256 + threadIdx.x;
    if (i >= n4) return;
    *(float4*)(out + (size_t)i * 4) = *(const float4*)(in + (size_t)i * 4);
}

// ---------------------------------------------------------------------------
// Generic GEMM: C[M,N] = A[M,K] @ W[N,K]^T (+bias) (+epilogue)
// A,W bf16; bias fp32; out bf16 (store epilogues) or fp32 += (add epilogues).
// 128x128 tile, 4 waves (2x2 of 64x64), mfma_f32_16x16x32_bf16
// ---------------------------------------------------------------------------
enum { EPI_STORE = 0, EPI_BIAS_STORE = 1, EPI_BIAS_GELU = 2, EPI_BIAS_ADD = 3, EPI_BIAS_ADD_TFC = 4 };

template <int EPI>
__global__ __launch_bounds__(256) void gemm_bt(
    const ushort* __restrict__ Ag, const ushort* __restrict__ Wg,
    const float* __restrict__ bias, ushort* __restrict__ Cg,
    float* __restrict__ xf, int M, int N, int K)
{
    __shared__ ushort As[128][40];   // 80B row stride: 16B-aligned, max 2-way bank alias
    __shared__ ushort Bs[128][40];

    const int tid  = threadIdx.x;
    const int lane = tid & 63, wid = tid >> 6;
    const int m0 = blockIdx.x * 128, n0 = blockIdx.y * 128;
    const int wm = (wid >> 1) * 64, wn = (wid & 1) * 64;
    const int fr = lane & 15, fq = lane >> 4;

    f32x4 acc[4][4] = {};

    for (int k0 = 0; k0 < K; k0 += 32) {
        #pragma unroll
        for (int i = 0; i < 2; ++i) {
            int chunk = tid + i * 256;          // 512 chunks of 8 bf16
            int r = chunk >> 2, c = (chunk & 3) << 3;
            uint4 va = {0u, 0u, 0u, 0u};
            if (m0 + r < M) va = *(const uint4*)(Ag + (size_t)(m0 + r) * K + k0 + c);
            *(uint4*)&As[r][c] = va;
            uint4 vb = *(const uint4*)(Wg + (size_t)(n0 + r) * K + k0 + c);
            *(uint4*)&Bs[r][c] = vb;
        }
        __syncthreads();

        bf16x8 af[4], bfr[4];
        #pragma unroll
        for (int i = 0; i < 4; ++i) af[i] = *(const bf16x8*)&As[wm + i * 16 + fr][fq * 8];
        #pragma unroll
        for (int j = 0; j < 4; ++j) bfr[j] = *(const bf16x8*)&Bs[wn + j * 16 + fr][fq * 8];
        #pragma unroll
        for (int i = 0; i < 4; ++i)
            #pragma unroll
            for (int j = 0; j < 4; ++j)
                acc[i][j] = __builtin_amdgcn_mfma_f32_16x16x32_bf16(af[i], bfr[j], acc[i][j], 0, 0, 0);
        __syncthreads();
    }

    // D row = wm + i*16 + fq*4 + e, col = wn + j*16 + fr  (verified C/D layout)
    #pragma unroll
    for (int i = 0; i < 4; ++i) {
        #pragma unroll
        for (int e = 0; e < 4; ++e) {
            int row = m0 + wm + i * 16 + fq * 4 + e;
            if (row >= M) continue;
            #pragma unroll
            for (int j = 0; j < 4; ++j) {
                int col = n0 + wn + j * 16 + fr;
                float v = acc[i][j][e];
                if constexpr (EPI != EPI_STORE) v += bias[col];
                if constexpr (EPI == EPI_BIAS_GELU) v = 0.5f * v * (1.0f + erff(v * 0.70710678118654752f));
                if constexpr (EPI == EPI_STORE || EPI == EPI_BIAS_STORE || EPI == EPI_BIAS_GELU) {
                    Cg[(size_t)row * N + col] = f2bf(v);
                } else {
                    int dst = row;
                    if constexpr (EPI == EPI_BIAS_ADD_TFC) {
                        // temporal row m = (b*196+p)*8 + t  ->  x row (b*8+t), token 1+p
                        int t = row & 7, pp = (row >> 3) % HW_, bb = row / (HW_ * T_);
                        dst = (bb * T_ + t) * NTOK + 1 + pp;
                    }
                    xf[(size_t)dst * DIM + col] += v;
                }
            }
        }
    }
}

// ---------------------------------------------------------------------------
// LayerNorm from fp32 src -> bf16 out (768 wide, 1 wave/row)
// ---------------------------------------------------------------------------
__global__ __launch_bounds__(256) void ln_f32(
    const float* __restrict__ src, const float* __restrict__ g,
    const float* __restrict__ b, ushort* __restrict__ dst, int rows)
{
    int widx = threadIdx.x >> 6, lane = threadIdx.x & 63;
    int r = blockIdx.x * 4 + widx;
    if (r >= rows) return;
    const float* row = src + (size_t)r * DIM;
    float v[12], sum = 0.f, sq = 0.f;
    #pragma unroll
    for (int c = 0; c < 3; ++c) {
        float4 t = *(const float4*)(row + c * 256 + lane * 4);
        v[c*4+0] = t.x; v[c*4+1] = t.y; v[c*4+2] = t.z; v[c*4+3] = t.w;
        sum += t.x + t.y + t.z + t.w;
        sq  += t.x*t.x + t.y*t.y + t.z*t.z + t.w*t.w;
    }
    sum = wred_sum(sum); sq = wred_sum(sq);
    float mean = sum * (1.f / DIM);
    float var  = sq * (1.f / DIM) - mean * mean;
    float rstd = rsqrtf(var + 1e-5f);
    #pragma unroll
    for (int c = 0; c < 3; ++c) {
        int idx = c * 256 + lane * 4;
        float4 gg = *(const float4*)(g + idx);
        float4 bb = *(const float4*)(b + idx);
        ushort4 o;
        o.x = f2bf((v[c*4+0] - mean) * rstd * gg.x + bb.x);
        o.y = f2bf((v[c*4+1] - mean) * rstd * gg.y + bb.y);
        o.z = f2bf((v[c*4+2] - mean) * rstd * gg.z + bb.z);
        o.w = f2bf((v[c*4+3] - mean) * rstd * gg.w + bb.w);
        *(ushort4*)(dst + (size_t)r * DIM + idx) = o;
    }
}

// Temporal gather + LN: out row r=(b*196+p)*8+t  <-  x[(b*8+t)][1+p][:]  (x fp32)
__global__ __launch_bounds__(256) void ln_gather(
    const float* __restrict__ x, const float* __restrict__ g,
    const float* __restrict__ b, ushort* __restrict__ dst, int rows)
{
    int widx = threadIdx.x >> 6, lane = threadIdx.x & 63;
    int r = blockIdx.x * 4 + widx;
    if (r >= rows) return;
    int t = r & 7, pp = (r >> 3) % HW_, bb = r / (HW_ * T_);
    const float* row = x + ((size_t)(bb * T_ + t) * NTOK + 1 + pp) * DIM;
    float v[12], sum = 0.f, sq = 0.f;
    #pragma unroll
    for (int c = 0; c < 3; ++c) {
        float4 t4 = *(const float4*)(row + c * 256 + lane * 4);
        v[c*4+0] = t4.x; v[c*4+1] = t4.y; v[c*4+2] = t4.z; v[c*4+3] = t4.w;
        sum += t4.x + t4.y + t4.z + t4.w;
        sq  += t4.x*t4.x + t4.y*t4.y + t4.z*t4.z + t4.w*t4.w;
    }
    sum = wred_sum(sum); sq = wred_sum(sq);
    float mean = sum * (1.f / DIM);
    float var  = sq * (1.f / DIM) - mean * mean;
    float rstd = rsqrtf(var + 1e-5f);
    #pragma unroll
    for (int c = 0; c < 3; ++c) {
        int idx = c * 256 + lane * 4;
        float4 gg = *(const float4*)(g + idx);
        float4 bb2 = *(const float4*)(b + idx);
        ushort4 o;
        o.x = f2bf((v[c*4+0] - mean) * rstd * gg.x + bb2.x);
        o.y = f2bf((v[c*4+1] - mean) * rstd * gg.y + bb2.y);
        o.z = f2bf((v[c*4+2] - mean) * rstd * gg.z + bb2.z);
        o.w = f2bf((v[c*4+3] - mean) * rstd * gg.w + bb2.w);
        *(ushort4*)(dst + (size_t)r * DIM + idx) = o;
    }
}

// ---------------------------------------------------------------------------
// Temporal attention: seq len 8, one wave per (seq, head); lane=(qi*8+kj)
// ---------------------------------------------------------------------------
__global__ __launch_bounds__(256) void attn_temporal(
    const ushort* __restrict__ qkv, ushort* __restrict__ O)
{
    int widx = threadIdx.x >> 6, lane = threadIdx.x & 63;
    int w = blockIdx.x * 4 + widx;          // 1568*12 = 18816 waves
    int s = w / NH, h = w % NH;
    int qi = lane >> 3, kj = lane & 7;

    const ushort* qrow = qkv + (size_t)(s * 8 + qi) * (3 * DIM) + h * HD;
    const ushort* krow = qkv + (size_t)(s * 8 + kj) * (3 * DIM) + DIM + h * HD;
    float d = 0.f;
    #pragma unroll
    for (int c = 0; c < 8; ++c) {
        uint4 qa = *(const uint4*)(qrow + c * 8);
        uint4 ka = *(const uint4*)(krow + c * 8);
        const ushort* qs = (const ushort*)&qa;
        const ushort* ks = (const ushort*)&ka;
        #pragma unroll
        for (int e = 0; e < 8; ++e) d += bf2f(qs[e]) * bf2f(ks[e]);
    }
    float sc = d * 0.125f;
    float mx = sc;
    #pragma unroll
    for (int m = 4; m; m >>= 1) mx = fmaxf(mx, __shfl_xor(mx, m));
    float p = expf(sc - mx);
    float sum = p;
    #pragma unroll
    for (int m = 4; m; m >>= 1) sum += __shfl_xor(sum, m);
    p /= sum;

    float o[8] = {};
    int base = lane & ~7;
    #pragma unroll
    for (int t = 0; t < 8; ++t) {
        float pt = __shfl(p, base + t);
        const ushort* vrow = qkv + (size_t)(s * 8 + t) * (3 * DIM) + 2 * DIM + h * HD + kj * 8;
        uint4 va = *(const uint4*)vrow;
        const ushort* vs = (const ushort*)&va;
        #pragma unroll
        for (int e = 0; e < 8; ++e) o[e] += pt * bf2f(vs[e]);
    }
    ushort out[8];
    #pragma unroll
    for (int e = 0; e < 8; ++e) out[e] = f2bf(o[e]);
    *(uint4*)(O + (size_t)(s * 8 + qi) * DIM + h * HD + kj * 8) = *(const uint4*)out;
}

// ---------------------------------------------------------------------------
// Spatial attention: seq len 197, one wave per query row.
// ---------------------------------------------------------------------------
__global__ __launch_bounds__(256) void attn_spatial(
    const ushort* __restrict__ qkv, ushort* __restrict__ O)
{
    __shared__ float pbuf[4][256];
    int widx = threadIdx.x >> 6, lane = threadIdx.x & 63;
    int w = blockIdx.x * 4 + widx;          // 64*12*197 = 151296 waves exactly
    int s = w / (NH * NTOK);
    int rem = w % (NH * NTOK);
    int h = rem / NTOK, qi = rem % NTOK;

    const ushort* qrow = qkv + (size_t)(s * NTOK + qi) * (3 * DIM) + h * HD;
    float q[64];
    #pragma unroll
    for (int c = 0; c < 8; ++c) {
        uint4 qa = *(const uint4*)(qrow + c * 8);
        const ushort* qs = (const ushort*)&qa;
        #pragma unroll
        for (int e = 0; e < 8; ++e) q[c * 8 + e] = bf2f(qs[e]);
    }

    float sc[4], mx = -1e30f;
    #pragma unroll
    for (int kk = 0; kk < 4; ++kk) {
        int j = lane + kk * 64;
        sc[kk] = -1e30f;
        if (j < NTOK) {
            const ushort* krow = qkv + (size_t)(s * NTOK + j) * (3 * DIM) + DIM + h * HD;
            float d = 0.f;
            #pragma unroll
            for (int c = 0; c < 8; ++c) {
                uint4 ka = *(const uint4*)(krow + c * 8);
                const ushort* ks = (const ushort*)&ka;
                #pragma unroll
                for (int e = 0; e < 8; ++e) d += q[c * 8 + e] * bf2f(ks[e]);
            }
            sc[kk] = d * 0.125f;
            mx = fmaxf(mx, sc[kk]);
        }
    }
    mx = wred_max(mx);
    float sum = 0.f;
    #pragma unroll
    for (int kk = 0; kk < 4; ++kk) {
        int j = lane + kk * 64;
        float p = (j < NTOK) ? expf(sc[kk] - mx) : 0.f;
        pbuf[widx][j] = p;
        sum += p;
    }
    sum = wred_sum(sum);
    float rdenom = 1.f / sum;

    float o = 0.f;
    const ushort* vbase = qkv + (size_t)(s * NTOK) * (3 * DIM) + 2 * DIM + h * HD + lane;
    for (int j = 0; j < NTOK; ++j)
        o += pbuf[widx][j] * bf2f(vbase[(size_t)j * (3 * DIM)]);

    O[(size_t)(s * NTOK + qi) * DIM + h * HD + lane] = f2bf(o * rdenom);
}

// ---------------------------------------------------------------------------
extern "C" void kernel_launch(void* const* d_in, const int* in_sizes, int n_in,
                              void* d_out, int out_size, void* d_ws, size_t ws_size,
                              hipStream_t stream)
{
    const float* x      = (const float*)d_in[0];
    const float* ln1_g  = (const float*)d_in[1];
    const float* ln1_b  = (const float*)d_in[2];
    const float* qkv_w  = (const float*)d_in[3];
    const float* proj_w = (const float*)d_in[4];
    const float* proj_b = (const float*)d_in[5];
    const float* tln_g  = (const float*)d_in[6];
    const float* tln_b  = (const float*)d_in[7];
    const float* tqkv_w = (const float*)d_in[8];
    const float* tproj_w= (const float*)d_in[9];
    const float* tproj_b= (const float*)d_in[10];
    const float* tfc_w  = (const float*)d_in[11];
    const float* tfc_b  = (const float*)d_in[12];
    const float* ln2_g  = (const float*)d_in[13];
    const float* ln2_b  = (const float*)d_in[14];
    const float* fc1_w  = (const float*)d_in[15];
    const float* fc1_b  = (const float*)d_in[16];
    const float* fc2_w  = (const float*)d_in[17];
    const float* fc2_b  = (const float*)d_in[18];

    float* out = (float*)d_out;   // fp32 residual accumulator = final output

    // bf16 weight copies + activation buffers in ws (~111 MB)
    char* p = (char*)d_ws;
    ushort* w_qkv  = (ushort*)p; p += (size_t)(3*DIM*DIM) * 2;
    ushort* w_proj = (ushort*)p; p += (size_t)(DIM*DIM) * 2;
    ushort* w_tqkv = (ushort*)p; p += (size_t)(3*DIM*DIM) * 2;
    ushort* w_tproj= (ushort*)p; p += (size_t)(DIM*DIM) * 2;
    ushort* w_tfc  = (ushort*)p; p += (size_t)(DIM*DIM) * 2;
    ushort* w_fc1  = (ushort*)p; p += (size_t)(HID*DIM) * 2;
    ushort* w_fc2  = (ushort*)p; p += (size_t)(HID*DIM) * 2;
    ushort* bufA   = (ushort*)p; p += (size_t)MROWS * DIM * 2;
    ushort* bufC   = (ushort*)p; p += (size_t)MROWS * DIM * 2;
    ushort* bufB   = (ushort*)p;  // MROWS*3*DIM bf16 (58.1 MB)

    // weight casts
    auto castw = [&](const float* src, ushort* dst, int elems) {
        int n8 = elems / 8;
        cast_w<<<dim3((n8 + 255) / 256), dim3(256), 0, stream>>>(src, dst, n8);
    };
    castw(qkv_w,  w_qkv,  3*DIM*DIM);
    castw(proj_w, w_proj, DIM*DIM);
    castw(tqkv_w, w_tqkv, 3*DIM*DIM);
    castw(tproj_w,w_tproj,DIM*DIM);
    castw(tfc_w,  w_tfc,  DIM*DIM);
    castw(fc1_w,  w_fc1,  HID*DIM);
    castw(fc2_w,  w_fc2,  HID*DIM);

    // residual init: out = x
    {
        int n4 = MROWS * DIM / 4;
        copy_f32<<<dim3((n4 + 255) / 256), dim3(256), 0, stream>>>(x, out, n4);
    }

    // ---- temporal branch (reads original x) ----
    ln_gather<<<dim3(TROWS / 4), dim3(256), 0, stream>>>(x, tln_g, tln_b, bufA, TROWS);
    gemm_bt<EPI_STORE><<<dim3(TROWS / 128, 18), dim3(256), 0, stream>>>(
        bufA, w_tqkv, nullptr, bufB, nullptr, TROWS, 3 * DIM, DIM);
    attn_temporal<<<dim3(TROWS * NH / 8 / 4), dim3(256), 0, stream>>>(bufB, bufC);
    gemm_bt<EPI_BIAS_STORE><<<dim3(TROWS / 128, 6), dim3(256), 0, stream>>>(
        bufC, w_tproj, tproj_b, bufA, nullptr, TROWS, DIM, DIM);
    gemm_bt<EPI_BIAS_ADD_TFC><<<dim3(TROWS / 128, 6), dim3(256), 0, stream>>>(
        bufA, w_tfc, tfc_b, nullptr, out, TROWS, DIM, DIM);

    // ---- spatial attention ----
    ln_f32<<<dim3((MROWS + 3) / 4), dim3(256), 0, stream>>>(out, ln1_g, ln1_b, bufA, MROWS);
    gemm_bt<EPI_STORE><<<dim3((MROWS + 127) / 128, 18), dim3(256), 0, stream>>>(
        bufA, w_qkv, nullptr, bufB, nullptr, MROWS, 3 * DIM, DIM);
    attn_spatial<<<dim3(BT_ * NH * NTOK / 4), dim3(256), 0, stream>>>(bufB, bufC);
    gemm_bt<EPI_BIAS_ADD><<<dim3((MROWS + 127) / 128, 6), dim3(256), 0, stream>>>(
        bufC, w_proj, proj_b, nullptr, out, MROWS, DIM, DIM);

    // ---- MLP ----
    ln_f32<<<dim3((MROWS + 3) / 4), dim3(256), 0, stream>>>(out, ln2_g, ln2_b, bufA, MROWS);
    gemm_bt<EPI_BIAS_GELU><<<dim3((MROWS + 127) / 128, 9), dim3(256), 0, stream>>>(
        bufA, w_fc1, fc1_b, bufB, nullptr, MROWS, HID, DIM);
    gemm_bt<EPI_BIAS_ADD><<<dim3((MROWS + 127) / 128, 6), dim3(256), 0, stream>>>(
        bufB, w_fc2, fc2_b, nullptr, out, MROWS, DIM, HID);
}

// Round 3
// 530.631 us; speedup vs baseline: 4.6044x; 4.6044x over previous
//
#include <hip/hip_runtime.h>
#include <hip/hip_bf16.h>

// ---------------------------------------------------------------------------
// FactorizedAttentionBlock (TimeSformer divided space-time attention)
// DIM=768, NH=12, HD=64, HID=1152, B=8, T=8, HW=196, N=197, BT=64
// FP32 in/out. bf16 MFMA GEMMs + MFMA flash attention. fp32 residual in d_out.
// ---------------------------------------------------------------------------

#define DIM   768
#define NH    12
#define HD    64
#define HID   1152
#define B_    8
#define T_    8
#define HW_   196
#define NTOK  197
#define BT_   64
#define MROWS (BT_ * NTOK)        // 12608
#define TROWS (B_ * HW_ * T_)     // 12544

typedef __bf16 bf16x8 __attribute__((ext_vector_type(8)));
typedef float  f32x4  __attribute__((ext_vector_type(4)));

__device__ inline float bf2f(ushort u) { return __uint_as_float(((unsigned)u) << 16); }
__device__ inline ushort f2bf(float f) {
    unsigned u = __float_as_uint(f);
    unsigned r = (u + 0x7fffu + ((u >> 16) & 1u)) >> 16;
    return (ushort)r;
}

__device__ inline float wred_sum(float v) {
    #pragma unroll
    for (int m = 32; m; m >>= 1) v += __shfl_xor(v, m);
    return v;
}

__device__ __forceinline__ void gload_lds16(const void* g, void* l) {
    __builtin_amdgcn_global_load_lds(
        (const __attribute__((address_space(1))) unsigned int*)g,
        (__attribute__((address_space(3))) unsigned int*)l, 16, 0, 0);
}

// ---------------------------------------------------------------------------
// casts / copies
// ---------------------------------------------------------------------------
__global__ __launch_bounds__(256) void cast_w(const float* __restrict__ in, ushort* __restrict__ out, int n8)
{
    int i = blockIdx.x * 256 + threadIdx.x;
    if (i >= n8) return;
    float4 a = *(const float4*)(in + (size_t)i * 8);
    float4 b = *(const float4*)(in + (size_t)i * 8 + 4);
    ushort o[8] = {f2bf(a.x), f2bf(a.y), f2bf(a.z), f2bf(a.w),
                   f2bf(b.x), f2bf(b.y), f2bf(b.z), f2bf(b.w)};
    *(uint4*)(out + (size_t)i * 8) = *(const uint4*)o;
}

__global__ __launch_bounds__(256) void copy_f32(const float* __restrict__ in, float* __restrict__ out, int n4)
{
    int i = blockIdx.x * 256 + threadIdx.x;
    if (i >= n4) return;
    *(float4*)(out + (size_t)i * 4) = *(const float4*)(in + (size_t)i * 4);
}

// ---------------------------------------------------------------------------
// GEMM: C[M,N] = A[M,K] @ W[N,K]^T (+bias)(+epi). 128x128 tile, 4 waves.
// Staging via global_load_lds width=16. N,K multiples of 128/32; M may tail.
// ---------------------------------------------------------------------------
enum { EPI_STORE = 0, EPI_BIAS_STORE = 1, EPI_BIAS_GELU = 2, EPI_BIAS_ADD = 3, EPI_BIAS_ADD_TFC = 4 };

template <int EPI>
__global__ __launch_bounds__(256) void gemm_bt(
    const ushort* __restrict__ Ag, const ushort* __restrict__ Wg,
    const float* __restrict__ bias, ushort* __restrict__ Cg,
    float* __restrict__ xf, int M, int N, int K)
{
    __shared__ ushort As[128 * 32];   // 8KB, rows of 64B (linear for gload_lds)
    __shared__ ushort Bs[128 * 32];

    const int tid  = threadIdx.x;
    const int lane = tid & 63, wid = tid >> 6;
    const int m0 = blockIdx.x * 128, n0 = blockIdx.y * 128;
    const int wm = (wid >> 1) * 64, wn = (wid & 1) * 64;
    const int fr = lane & 15, fq = lane >> 4;

    f32x4 acc[4][4] = {};

    const int lrow = lane >> 2;          // 0..15 within 16-row segment
    const int lcol = (lane & 3) * 8;     // elem col 0/8/16/24

    for (int k0 = 0; k0 < K; k0 += 32) {
        #pragma unroll
        for (int i = 0; i < 2; ++i) {
            int seg = wid * 2 + i;                  // 0..7: 16 rows each
            int r = seg * 16 + lrow;
            int ar = m0 + r; if (ar >= M) ar = M - 1;   // clamp tail rows
            gload_lds16(Ag + (size_t)ar * K + k0 + lcol, &As[seg * 512]);
            gload_lds16(Wg + (size_t)(n0 + r) * K + k0 + lcol, &Bs[seg * 512]);
        }
        __syncthreads();

        bf16x8 af[4], bfr[4];
        #pragma unroll
        for (int i = 0; i < 4; ++i) af[i] = *(const bf16x8*)&As[(wm + i * 16 + fr) * 32 + fq * 8];
        #pragma unroll
        for (int j = 0; j < 4; ++j) bfr[j] = *(const bf16x8*)&Bs[(wn + j * 16 + fr) * 32 + fq * 8];
        #pragma unroll
        for (int i = 0; i < 4; ++i)
            #pragma unroll
            for (int j = 0; j < 4; ++j)
                acc[i][j] = __builtin_amdgcn_mfma_f32_16x16x32_bf16(af[i], bfr[j], acc[i][j], 0, 0, 0);
        __syncthreads();
    }

    // D row = wm + i*16 + fq*4 + e, col = wn + j*16 + fr
    #pragma unroll
    for (int i = 0; i < 4; ++i) {
        #pragma unroll
        for (int e = 0; e < 4; ++e) {
            int row = m0 + wm + i * 16 + fq * 4 + e;
            if (row >= M) continue;
            #pragma unroll
            for (int j = 0; j < 4; ++j) {
                int col = n0 + wn + j * 16 + fr;
                float v = acc[i][j][e];
                if constexpr (EPI != EPI_STORE) v += bias[col];
                if constexpr (EPI == EPI_BIAS_GELU) v = 0.5f * v * (1.0f + erff(v * 0.70710678118654752f));
                if constexpr (EPI == EPI_STORE || EPI == EPI_BIAS_STORE || EPI == EPI_BIAS_GELU) {
                    Cg[(size_t)row * N + col] = f2bf(v);
                } else {
                    int dst = row;
                    if constexpr (EPI == EPI_BIAS_ADD_TFC) {
                        int t = row & 7, pp = (row >> 3) % HW_, bb = row / (HW_ * T_);
                        dst = (bb * T_ + t) * NTOK + 1 + pp;
                    }
                    xf[(size_t)dst * DIM + col] += v;
                }
            }
        }
    }
}

// ---------------------------------------------------------------------------
// LayerNorm fp32 src -> bf16 dst (768 wide, 1 wave/row)
// ---------------------------------------------------------------------------
__global__ __launch_bounds__(256) void ln_f32(
    const float* __restrict__ src, const float* __restrict__ g,
    const float* __restrict__ b, ushort* __restrict__ dst, int rows)
{
    int widx = threadIdx.x >> 6, lane = threadIdx.x & 63;
    int r = blockIdx.x * 4 + widx;
    if (r >= rows) return;
    const float* row = src + (size_t)r * DIM;
    float v[12], sum = 0.f, sq = 0.f;
    #pragma unroll
    for (int c = 0; c < 3; ++c) {
        float4 t = *(const float4*)(row + c * 256 + lane * 4);
        v[c*4+0] = t.x; v[c*4+1] = t.y; v[c*4+2] = t.z; v[c*4+3] = t.w;
        sum += t.x + t.y + t.z + t.w;
        sq  += t.x*t.x + t.y*t.y + t.z*t.z + t.w*t.w;
    }
    sum = wred_sum(sum); sq = wred_sum(sq);
    float mean = sum * (1.f / DIM);
    float var  = sq * (1.f / DIM) - mean * mean;
    float rstd = rsqrtf(var + 1e-5f);
    #pragma unroll
    for (int c = 0; c < 3; ++c) {
        int idx = c * 256 + lane * 4;
        float4 gg = *(const float4*)(g + idx);
        float4 bb = *(const float4*)(b + idx);
        ushort4 o;
        o.x = f2bf((v[c*4+0] - mean) * rstd * gg.x + bb.x);
        o.y = f2bf((v[c*4+1] - mean) * rstd * gg.y + bb.y);
        o.z = f2bf((v[c*4+2] - mean) * rstd * gg.z + bb.z);
        o.w = f2bf((v[c*4+3] - mean) * rstd * gg.w + bb.w);
        *(ushort4*)(dst + (size_t)r * DIM + idx) = o;
    }
}

// Temporal gather + LN: out row r=(b*196+p)*8+t  <-  x[(b*8+t)][1+p][:]
__global__ __launch_bounds__(256) void ln_gather(
    const float* __restrict__ x, const float* __restrict__ g,
    const float* __restrict__ b, ushort* __restrict__ dst, int rows)
{
    int widx = threadIdx.x >> 6, lane = threadIdx.x & 63;
    int r = blockIdx.x * 4 + widx;
    if (r >= rows) return;
    int t = r & 7, pp = (r >> 3) % HW_, bb = r / (HW_ * T_);
    const float* row = x + ((size_t)(bb * T_ + t) * NTOK + 1 + pp) * DIM;
    float v[12], sum = 0.f, sq = 0.f;
    #pragma unroll
    for (int c = 0; c < 3; ++c) {
        float4 t4 = *(const float4*)(row + c * 256 + lane * 4);
        v[c*4+0] = t4.x; v[c*4+1] = t4.y; v[c*4+2] = t4.z; v[c*4+3] = t4.w;
        sum += t4.x + t4.y + t4.z + t4.w;
        sq  += t4.x*t4.x + t4.y*t4.y + t4.z*t4.z + t4.w*t4.w;
    }
    sum = wred_sum(sum); sq = wred_sum(sq);
    float mean = sum * (1.f / DIM);
    float var  = sq * (1.f / DIM) - mean * mean;
    float rstd = rsqrtf(var + 1e-5f);
    #pragma unroll
    for (int c = 0; c < 3; ++c) {
        int idx = c * 256 + lane * 4;
        float4 gg = *(const float4*)(g + idx);
        float4 bb2 = *(const float4*)(b + idx);
        ushort4 o;
        o.x = f2bf((v[c*4+0] - mean) * rstd * gg.x + bb2.x);
        o.y = f2bf((v[c*4+1] - mean) * rstd * gg.y + bb2.y);
        o.z = f2bf((v[c*4+2] - mean) * rstd * gg.z + bb2.z);
        o.w = f2bf((v[c*4+3] - mean) * rstd * gg.w + bb2.w);
        *(ushort4*)(dst + (size_t)r * DIM + idx) = o;
    }
}

// ---------------------------------------------------------------------------
// Temporal attention: seq len 8, one wave per (seq, head); lane=(qi*8+kj)
// ---------------------------------------------------------------------------
__global__ __launch_bounds__(256) void attn_temporal(
    const ushort* __restrict__ qkv, ushort* __restrict__ O)
{
    int widx = threadIdx.x >> 6, lane = threadIdx.x & 63;
    int w = blockIdx.x * 4 + widx;
    int s = w / NH, h = w % NH;
    int qi = lane >> 3, kj = lane & 7;

    const ushort* qrow = qkv + (size_t)(s * 8 + qi) * (3 * DIM) + h * HD;
    const ushort* krow = qkv + (size_t)(s * 8 + kj) * (3 * DIM) + DIM + h * HD;
    float d = 0.f;
    #pragma unroll
    for (int c = 0; c < 8; ++c) {
        uint4 qa = *(const uint4*)(qrow + c * 8);
        uint4 ka = *(const uint4*)(krow + c * 8);
        const ushort* qs = (const ushort*)&qa;
        const ushort* ks = (const ushort*)&ka;
        #pragma unroll
        for (int e = 0; e < 8; ++e) d += bf2f(qs[e]) * bf2f(ks[e]);
    }
    float sc = d * 0.125f;
    float mx = sc;
    #pragma unroll
    for (int m = 4; m; m >>= 1) mx = fmaxf(mx, __shfl_xor(mx, m));
    float p = expf(sc - mx);
    float sum = p;
    #pragma unroll
    for (int m = 4; m; m >>= 1) sum += __shfl_xor(sum, m);
    p /= sum;

    float o[8] = {};
    int base = lane & ~7;
    #pragma unroll
    for (int t = 0; t < 8; ++t) {
        float pt = __shfl(p, base + t);
        const ushort* vrow = qkv + (size_t)(s * 8 + t) * (3 * DIM) + 2 * DIM + h * HD + kj * 8;
        uint4 va = *(const uint4*)vrow;
        const ushort* vs = (const ushort*)&va;
        #pragma unroll
        for (int e = 0; e < 8; ++e) o[e] += pt * bf2f(vs[e]);
    }
    ushort out[8];
    #pragma unroll
    for (int e = 0; e < 8; ++e) out[e] = f2bf(o[e]);
    *(uint4*)(O + (size_t)(s * 8 + qi) * DIM + h * HD + kj * 8) = *(const uint4*)out;
}

// ---------------------------------------------------------------------------
// Spatial attention, MFMA. One block per (s,h); 4 waves; 768 blocks.
// K in LDS [197][72]; V transposed [64][208] (cols 197..207 zero);
// P per-wave [16][208]. Swapped QK^T (S^T in regs) -> in-lane softmax -> PV.
// LDS total 79.7KB -> 2 blocks/CU.
// ---------------------------------------------------------------------------
#define KS_STRIDE 72
#define VT_STRIDE 208
#define P_STRIDE  208
#define KS_OFF    0
#define VT_OFF    (197 * KS_STRIDE)                 // 14184
#define P_OFF     (VT_OFF + 64 * VT_STRIDE)         // 27496
#define LDS_TOT   (P_OFF + 4 * 16 * P_STRIDE)       // 40808 ushorts = 79.7KB

__global__ __launch_bounds__(256, 2) void attn_spatial_mfma(
    const ushort* __restrict__ qkv, ushort* __restrict__ O)
{
    __shared__ ushort lds[LDS_TOT];
    const int tid = threadIdx.x, lane = tid & 63, wid = tid >> 6;
    const int fr = lane & 15, fq = lane >> 4;
    const int s = blockIdx.x / NH, h = blockIdx.x % NH;
    const size_t base = (size_t)s * NTOK * (3 * DIM);
    const ushort* Qg = qkv + base + h * HD;
    const ushort* Kg = qkv + base + DIM + h * HD;
    const ushort* Vg = qkv + base + 2 * DIM + h * HD;

    // stage K rows (197, no pad fill needed; tail masked later)
    for (int chunk = tid; chunk < NTOK * 8; chunk += 256) {
        int r = chunk >> 3, c = (chunk & 7) * 8;
        uint4 v = *(const uint4*)(Kg + (size_t)r * (3 * DIM) + c);
        *(uint4*)&lds[KS_OFF + r * KS_STRIDE + c] = v;
    }
    // stage V transposed; zero cols 197..207
    for (int chunk = tid; chunk < 208 * 8; chunk += 256) {
        int k = chunk >> 3, c = (chunk & 7) * 8;
        uint4 v = {0u, 0u, 0u, 0u};
        if (k < NTOK) v = *(const uint4*)(Vg + (size_t)k * (3 * DIM) + c);
        const ushort* e = (const ushort*)&v;
        #pragma unroll
        for (int j = 0; j < 8; ++j) lds[VT_OFF + (c + j) * VT_STRIDE + k] = e[j];
    }
    __syncthreads();

    ushort* P = &lds[P_OFF + wid * 16 * P_STRIDE];

    for (int qi = wid; qi < 13; qi += 4) {
        // Q fragments from global (B operand), row-clamped
        int qrow = qi * 16 + fr; if (qrow > NTOK - 1) qrow = NTOK - 1;
        bf16x8 qf0 = *(const bf16x8*)(Qg + (size_t)qrow * (3 * DIM) + fq * 8);
        bf16x8 qf1 = *(const bf16x8*)(Qg + (size_t)qrow * (3 * DIM) + 32 + fq * 8);

        // QK^T swapped: sacc[t] = S^T tile; lane holds key=16t+4fq+e, q=qi*16+fr
        f32x4 sacc[13];
        #pragma unroll
        for (int t = 0; t < 13; ++t) {
            bf16x8 kf0 = *(const bf16x8*)&lds[KS_OFF + (t * 16 + fr) * KS_STRIDE + fq * 8];
            bf16x8 kf1 = *(const bf16x8*)&lds[KS_OFF + (t * 16 + fr) * KS_STRIDE + 32 + fq * 8];
            f32x4 z = {0.f, 0.f, 0.f, 0.f};
            z = __builtin_amdgcn_mfma_f32_16x16x32_bf16(kf0, qf0, z, 0, 0, 0);
            sacc[t] = __builtin_amdgcn_mfma_f32_16x16x32_bf16(kf1, qf1, z, 0, 0, 0);
        }

        // in-lane softmax over k, then 2 shuffles across fq groups
        float m = -1e30f;
        #pragma unroll
        for (int t = 0; t < 13; ++t)
            #pragma unroll
            for (int e = 0; e < 4; ++e) {
                int k = t * 16 + fq * 4 + e;
                float v = (k < NTOK) ? sacc[t][e] * 0.125f : -1e30f;
                sacc[t][e] = v;
                m = fmaxf(m, v);
            }
        m = fmaxf(m, __shfl_xor(m, 16));
        m = fmaxf(m, __shfl_xor(m, 32));
        float sum = 0.f;
        #pragma unroll
        for (int t = 0; t < 13; ++t)
            #pragma unroll
            for (int e = 0; e < 4; ++e) {
                float p = expf(sacc[t][e] - m);   // masked entries underflow to 0
                sacc[t][e] = p;
                sum += p;
            }
        sum += __shfl_xor(sum, 16);
        sum += __shfl_xor(sum, 32);
        float rd = 1.f / sum;

        // write normalized P (bf16) to per-wave LDS tile
        #pragma unroll
        for (int t = 0; t < 13; ++t) {
            ushort2 w0 = { f2bf(sacc[t][0] * rd), f2bf(sacc[t][1] * rd) };
            ushort2 w1 = { f2bf(sacc[t][2] * rd), f2bf(sacc[t][3] * rd) };
            *(ushort2*)&P[fr * P_STRIDE + t * 16 + fq * 4]     = w0;
            *(ushort2*)&P[fr * P_STRIDE + t * 16 + fq * 4 + 2] = w1;
        }

        // PV: O[q][d] = P @ Vt^T ; 6 full k-steps + 16-wide tail (fq<2 lanes)
        f32x4 oacc[4] = {};
        #pragma unroll
        for (int st = 0; st < 6; ++st) {
            bf16x8 pf = *(const bf16x8*)&P[fr * P_STRIDE + st * 32 + fq * 8];
            #pragma unroll
            for (int dt = 0; dt < 4; ++dt) {
                bf16x8 vf = *(const bf16x8*)&lds[VT_OFF + (dt * 16 + fr) * VT_STRIDE + st * 32 + fq * 8];
                oacc[dt] = __builtin_amdgcn_mfma_f32_16x16x32_bf16(pf, vf, oacc[dt], 0, 0, 0);
            }
        }
        {
            bf16x8 zz = {};
            bf16x8 pf = zz;
            if (fq < 2) pf = *(const bf16x8*)&P[fr * P_STRIDE + 192 + fq * 8];
            #pragma unroll
            for (int dt = 0; dt < 4; ++dt) {
                bf16x8 vf = zz;
                if (fq < 2) vf = *(const bf16x8*)&lds[VT_OFF + (dt * 16 + fr) * VT_STRIDE + 192 + fq * 8];
                oacc[dt] = __builtin_amdgcn_mfma_f32_16x16x32_bf16(pf, vf, oacc[dt], 0, 0, 0);
            }
        }

        // store O tile: row q = qi*16 + 4fq + e, col d = 16dt + fr
        #pragma unroll
        for (int dt = 0; dt < 4; ++dt)
            #pragma unroll
            for (int e = 0; e < 4; ++e) {
                int q = qi * 16 + fq * 4 + e;
                if (q < NTOK)
                    O[(size_t)(s * NTOK + q) * DIM + h * HD + dt * 16 + fr] = f2bf(oacc[dt][e]);
            }
    }
}

// ---------------------------------------------------------------------------
extern "C" void kernel_launch(void* const* d_in, const int* in_sizes, int n_in,
                              void* d_out, int out_size, void* d_ws, size_t ws_size,
                              hipStream_t stream)
{
    const float* x      = (const float*)d_in[0];
    const float* ln1_g  = (const float*)d_in[1];
    const float* ln1_b  = (const float*)d_in[2];
    const float* qkv_w  = (const float*)d_in[3];
    const float* proj_w = (const float*)d_in[4];
    const float* proj_b = (const float*)d_in[5];
    const float* tln_g  = (const float*)d_in[6];
    const float* tln_b  = (const float*)d_in[7];
    const float* tqkv_w = (const float*)d_in[8];
    const float* tproj_w= (const float*)d_in[9];
    const float* tproj_b= (const float*)d_in[10];
    const float* tfc_w  = (const float*)d_in[11];
    const float* tfc_b  = (const float*)d_in[12];
    const float* ln2_g  = (const float*)d_in[13];
    const float* ln2_b  = (const float*)d_in[14];
    const float* fc1_w  = (const float*)d_in[15];
    const float* fc1_b  = (const float*)d_in[16];
    const float* fc2_w  = (const float*)d_in[17];
    const float* fc2_b  = (const float*)d_in[18];

    float* out = (float*)d_out;   // fp32 residual accumulator = final output

    char* p = (char*)d_ws;
    ushort* w_qkv  = (ushort*)p; p += (size_t)(3*DIM*DIM) * 2;
    ushort* w_proj = (ushort*)p; p += (size_t)(DIM*DIM) * 2;
    ushort* w_tqkv = (ushort*)p; p += (size_t)(3*DIM*DIM) * 2;
    ushort* w_tproj= (ushort*)p; p += (size_t)(DIM*DIM) * 2;
    ushort* w_tfc  = (ushort*)p; p += (size_t)(DIM*DIM) * 2;
    ushort* w_fc1  = (ushort*)p; p += (size_t)(HID*DIM) * 2;
    ushort* w_fc2  = (ushort*)p; p += (size_t)(HID*DIM) * 2;
    ushort* bufA   = (ushort*)p; p += (size_t)MROWS * DIM * 2;
    ushort* bufC   = (ushort*)p; p += (size_t)MROWS * DIM * 2;
    ushort* bufB   = (ushort*)p;  // MROWS*3*DIM bf16

    auto castw = [&](const float* src, ushort* dst, int elems) {
        int n8 = elems / 8;
        cast_w<<<dim3((n8 + 255) / 256), dim3(256), 0, stream>>>(src, dst, n8);
    };
    castw(qkv_w,  w_qkv,  3*DIM*DIM);
    castw(proj_w, w_proj, DIM*DIM);
    castw(tqkv_w, w_tqkv, 3*DIM*DIM);
    castw(tproj_w,w_tproj,DIM*DIM);
    castw(tfc_w,  w_tfc,  DIM*DIM);
    castw(fc1_w,  w_fc1,  HID*DIM);
    castw(fc2_w,  w_fc2,  HID*DIM);

    {
        int n4 = MROWS * DIM / 4;
        copy_f32<<<dim3((n4 + 255) / 256), dim3(256), 0, stream>>>(x, out, n4);
    }

    // ---- temporal branch ----
    ln_gather<<<dim3(TROWS / 4), dim3(256), 0, stream>>>(x, tln_g, tln_b, bufA, TROWS);
    gemm_bt<EPI_STORE><<<dim3(TROWS / 128, 18), dim3(256), 0, stream>>>(
        bufA, w_tqkv, nullptr, bufB, nullptr, TROWS, 3 * DIM, DIM);
    attn_temporal<<<dim3(TROWS * NH / 8 / 4), dim3(256), 0, stream>>>(bufB, bufC);
    gemm_bt<EPI_BIAS_STORE><<<dim3(TROWS / 128, 6), dim3(256), 0, stream>>>(
        bufC, w_tproj, tproj_b, bufA, nullptr, TROWS, DIM, DIM);
    gemm_bt<EPI_BIAS_ADD_TFC><<<dim3(TROWS / 128, 6), dim3(256), 0, stream>>>(
        bufA, w_tfc, tfc_b, nullptr, out, TROWS, DIM, DIM);

    // ---- spatial attention ----
    ln_f32<<<dim3((MROWS + 3) / 4), dim3(256), 0, stream>>>(out, ln1_g, ln1_b, bufA, MROWS);
    gemm_bt<EPI_STORE><<<dim3((MROWS + 127) / 128, 18), dim3(256), 0, stream>>>(
        bufA, w_qkv, nullptr, bufB, nullptr, MROWS, 3 * DIM, DIM);
    attn_spatial_mfma<<<dim3(BT_ * NH), dim3(256), 0, stream>>>(bufB, bufC);
    gemm_bt<EPI_BIAS_ADD><<<dim3((MROWS + 127) / 128, 6), dim3(256), 0, stream>>>(
        bufC, w_proj, proj_b, nullptr, out, MROWS, DIM, DIM);

    // ---- MLP ----
    ln_f32<<<dim3((MROWS + 3) / 4), dim3(256), 0, stream>>>(out, ln2_g, ln2_b, bufA, MROWS);
    gemm_bt<EPI_BIAS_GELU><<<dim3((MROWS + 127) / 128, 9), dim3(256), 0, stream>>>(
        bufA, w_fc1, fc1_b, bufB, nullptr, MROWS, HID, DIM);
    gemm_bt<EPI_BIAS_ADD><<<dim3((MROWS + 127) / 128, 6), dim3(256), 0, stream>>>(
        bufB, w_fc2, fc2_b, nullptr, out, MROWS, DIM, HID);
}

// Round 4
// 499.206 us; speedup vs baseline: 4.8942x; 1.0629x over previous
//
#include <hip/hip_runtime.h>
#include <hip/hip_bf16.h>

// ---------------------------------------------------------------------------
// FactorizedAttentionBlock (TimeSformer divided space-time attention)
// DIM=768, NH=12, HD=64, HID=1152, B=8, T=8, HW=196, N=197, BT=64
// FP32 in/out. bf16 MFMA GEMMs + MFMA flash attention. fp32 residual in d_out.
// R4: grouped + XCD-bijective block swizzle on all GEMMs (L2 over-fetch fix).
// ---------------------------------------------------------------------------

#define DIM   768
#define NH    12
#define HD    64
#define HID   1152
#define B_    8
#define T_    8
#define HW_   196
#define NTOK  197
#define BT_   64
#define MROWS (BT_ * NTOK)        // 12608
#define TROWS (B_ * HW_ * T_)     // 12544

typedef __bf16 bf16x8 __attribute__((ext_vector_type(8)));
typedef float  f32x4  __attribute__((ext_vector_type(4)));

__device__ inline float bf2f(ushort u) { return __uint_as_float(((unsigned)u) << 16); }
__device__ inline ushort f2bf(float f) {
    unsigned u = __float_as_uint(f);
    unsigned r = (u + 0x7fffu + ((u >> 16) & 1u)) >> 16;
    return (ushort)r;
}

__device__ inline float wred_sum(float v) {
    #pragma unroll
    for (int m = 32; m; m >>= 1) v += __shfl_xor(v, m);
    return v;
}

__device__ __forceinline__ void gload_lds16(const void* g, void* l) {
    __builtin_amdgcn_global_load_lds(
        (const __attribute__((address_space(1))) unsigned int*)g,
        (__attribute__((address_space(3))) unsigned int*)l, 16, 0, 0);
}

// XCD-bijective remap (m204): dispatch order round-robins XCDs; this gives
// each XCD a contiguous range of `lin` ids.
__device__ __forceinline__ int xcd_lin(int gid, int nwg) {
    int q = nwg >> 3, r = nwg & 7;
    int xcd = gid & 7, idx = gid >> 3;
    return (xcd < r ? xcd * (q + 1) : r * (q + 1) + (xcd - r) * q) + idx;
}

// ---------------------------------------------------------------------------
// casts / copies
// ---------------------------------------------------------------------------
__global__ __launch_bounds__(256) void cast_w(const float* __restrict__ in, ushort* __restrict__ out, int n8)
{
    int i = blockIdx.x * 256 + threadIdx.x;
    if (i >= n8) return;
    float4 a = *(const float4*)(in + (size_t)i * 8);
    float4 b = *(const float4*)(in + (size_t)i * 8 + 4);
    ushort o[8] = {f2bf(a.x), f2bf(a.y), f2bf(a.z), f2bf(a.w),
                   f2bf(b.x), f2bf(b.y), f2bf(b.z), f2bf(b.w)};
    *(uint4*)(out + (size_t)i * 8) = *(const uint4*)o;
}

__global__ __launch_bounds__(256) void copy_f32(const float* __restrict__ in, float* __restrict__ out, int n4)
{
    int i = blockIdx.x * 256 + threadIdx.x;
    if (i >= n4) return;
    *(float4*)(out + (size_t)i * 4) = *(const float4*)(in + (size_t)i * 4);
}

// ---------------------------------------------------------------------------
// GEMM: C[M,N] = A[M,K] @ W[N,K]^T (+bias)(+epi). 128x128 tile, 4 waves.
// 1D grid = nm*nn with grouped rasterization: GROUP_M m-tiles per group,
// n fastest within a group, groups laid contiguously per XCD.
// ---------------------------------------------------------------------------
enum { EPI_STORE = 0, EPI_BIAS_STORE = 1, EPI_BIAS_GELU = 2, EPI_BIAS_ADD = 3, EPI_BIAS_ADD_TFC = 4 };

template <int EPI>
__global__ __launch_bounds__(256) void gemm_bt(
    const ushort* __restrict__ Ag, const ushort* __restrict__ Wg,
    const float* __restrict__ bias, ushort* __restrict__ Cg,
    float* __restrict__ xf, int M, int N, int K,
    int nm, int nn, int grp)
{
    __shared__ ushort As[128 * 32];   // 8KB, rows of 64B (linear for gload_lds)
    __shared__ ushort Bs[128 * 32];

    const int tid  = threadIdx.x;
    const int lane = tid & 63, wid = tid >> 6;

    // grouped + XCD swizzle
    int lin = xcd_lin(blockIdx.x, nm * nn);
    int per = grp * nn;
    int g2 = lin / per, rem = lin % per;
    int bm = g2 * grp;
    int gm = nm - bm; if (gm > grp) gm = grp;
    const int m0 = (bm + rem % gm) * 128;
    const int n0 = (rem / gm) * 128;

    const int wm = (wid >> 1) * 64, wn = (wid & 1) * 64;
    const int fr = lane & 15, fq = lane >> 4;

    f32x4 acc[4][4] = {};

    const int lrow = lane >> 2;          // 0..15 within 16-row segment
    const int lcol = (lane & 3) * 8;     // elem col 0/8/16/24

    for (int k0 = 0; k0 < K; k0 += 32) {
        #pragma unroll
        for (int i = 0; i < 2; ++i) {
            int seg = wid * 2 + i;                  // 0..7: 16 rows each
            int r = seg * 16 + lrow;
            int ar = m0 + r; if (ar >= M) ar = M - 1;   // clamp tail rows
            gload_lds16(Ag + (size_t)ar * K + k0 + lcol, &As[seg * 512]);
            gload_lds16(Wg + (size_t)(n0 + r) * K + k0 + lcol, &Bs[seg * 512]);
        }
        __syncthreads();

        bf16x8 af[4], bfr[4];
        #pragma unroll
        for (int i = 0; i < 4; ++i) af[i] = *(const bf16x8*)&As[(wm + i * 16 + fr) * 32 + fq * 8];
        #pragma unroll
        for (int j = 0; j < 4; ++j) bfr[j] = *(const bf16x8*)&Bs[(wn + j * 16 + fr) * 32 + fq * 8];
        #pragma unroll
        for (int i = 0; i < 4; ++i)
            #pragma unroll
            for (int j = 0; j < 4; ++j)
                acc[i][j] = __builtin_amdgcn_mfma_f32_16x16x32_bf16(af[i], bfr[j], acc[i][j], 0, 0, 0);
        __syncthreads();
    }

    // D row = wm + i*16 + fq*4 + e, col = wn + j*16 + fr
    #pragma unroll
    for (int i = 0; i < 4; ++i) {
        #pragma unroll
        for (int e = 0; e < 4; ++e) {
            int row = m0 + wm + i * 16 + fq * 4 + e;
            if (row >= M) continue;
            #pragma unroll
            for (int j = 0; j < 4; ++j) {
                int col = n0 + wn + j * 16 + fr;
                float v = acc[i][j][e];
                if constexpr (EPI != EPI_STORE) v += bias[col];
                if constexpr (EPI == EPI_BIAS_GELU) v = 0.5f * v * (1.0f + erff(v * 0.70710678118654752f));
                if constexpr (EPI == EPI_STORE || EPI == EPI_BIAS_STORE || EPI == EPI_BIAS_GELU) {
                    Cg[(size_t)row * N + col] = f2bf(v);
                } else {
                    int dst = row;
                    if constexpr (EPI == EPI_BIAS_ADD_TFC) {
                        int t = row & 7, pp = (row >> 3) % HW_, bb = row / (HW_ * T_);
                        dst = (bb * T_ + t) * NTOK + 1 + pp;
                    }
                    xf[(size_t)dst * DIM + col] += v;
                }
            }
        }
    }
}

// ---------------------------------------------------------------------------
// LayerNorm fp32 src -> bf16 dst (768 wide, 1 wave/row)
// ---------------------------------------------------------------------------
__global__ __launch_bounds__(256) void ln_f32(
    const float* __restrict__ src, const float* __restrict__ g,
    const float* __restrict__ b, ushort* __restrict__ dst, int rows)
{
    int widx = threadIdx.x >> 6, lane = threadIdx.x & 63;
    int r = blockIdx.x * 4 + widx;
    if (r >= rows) return;
    const float* row = src + (size_t)r * DIM;
    float v[12], sum = 0.f, sq = 0.f;
    #pragma unroll
    for (int c = 0; c < 3; ++c) {
        float4 t = *(const float4*)(row + c * 256 + lane * 4);
        v[c*4+0] = t.x; v[c*4+1] = t.y; v[c*4+2] = t.z; v[c*4+3] = t.w;
        sum += t.x + t.y + t.z + t.w;
        sq  += t.x*t.x + t.y*t.y + t.z*t.z + t.w*t.w;
    }
    sum = wred_sum(sum); sq = wred_sum(sq);
    float mean = sum * (1.f / DIM);
    float var  = sq * (1.f / DIM) - mean * mean;
    float rstd = rsqrtf(var + 1e-5f);
    #pragma unroll
    for (int c = 0; c < 3; ++c) {
        int idx = c * 256 + lane * 4;
        float4 gg = *(const float4*)(g + idx);
        float4 bb = *(const float4*)(b + idx);
        ushort4 o;
        o.x = f2bf((v[c*4+0] - mean) * rstd * gg.x + bb.x);
        o.y = f2bf((v[c*4+1] - mean) * rstd * gg.y + bb.y);
        o.z = f2bf((v[c*4+2] - mean) * rstd * gg.z + bb.z);
        o.w = f2bf((v[c*4+3] - mean) * rstd * gg.w + bb.w);
        *(ushort4*)(dst + (size_t)r * DIM + idx) = o;
    }
}

// Temporal gather + LN: out row r=(b*196+p)*8+t  <-  x[(b*8+t)][1+p][:]
__global__ __launch_bounds__(256) void ln_gather(
    const float* __restrict__ x, const float* __restrict__ g,
    const float* __restrict__ b, ushort* __restrict__ dst, int rows)
{
    int widx = threadIdx.x >> 6, lane = threadIdx.x & 63;
    int r = blockIdx.x * 4 + widx;
    if (r >= rows) return;
    int t = r & 7, pp = (r >> 3) % HW_, bb = r / (HW_ * T_);
    const float* row = x + ((size_t)(bb * T_ + t) * NTOK + 1 + pp) * DIM;
    float v[12], sum = 0.f, sq = 0.f;
    #pragma unroll
    for (int c = 0; c < 3; ++c) {
        float4 t4 = *(const float4*)(row + c * 256 + lane * 4);
        v[c*4+0] = t4.x; v[c*4+1] = t4.y; v[c*4+2] = t4.z; v[c*4+3] = t4.w;
        sum += t4.x + t4.y + t4.z + t4.w;
        sq  += t4.x*t4.x + t4.y*t4.y + t4.z*t4.z + t4.w*t4.w;
    }
    sum = wred_sum(sum); sq = wred_sum(sq);
    float mean = sum * (1.f / DIM);
    float var  = sq * (1.f / DIM) - mean * mean;
    float rstd = rsqrtf(var + 1e-5f);
    #pragma unroll
    for (int c = 0; c < 3; ++c) {
        int idx = c * 256 + lane * 4;
        float4 gg = *(const float4*)(g + idx);
        float4 bb2 = *(const float4*)(b + idx);
        ushort4 o;
        o.x = f2bf((v[c*4+0] - mean) * rstd * gg.x + bb2.x);
        o.y = f2bf((v[c*4+1] - mean) * rstd * gg.y + bb2.y);
        o.z = f2bf((v[c*4+2] - mean) * rstd * gg.z + bb2.z);
        o.w = f2bf((v[c*4+3] - mean) * rstd * gg.w + bb2.w);
        *(ushort4*)(dst + (size_t)r * DIM + idx) = o;
    }
}

// ---------------------------------------------------------------------------
// Temporal attention: seq len 8, one wave per (seq, head); lane=(qi*8+kj)
// ---------------------------------------------------------------------------
__global__ __launch_bounds__(256) void attn_temporal(
    const ushort* __restrict__ qkv, ushort* __restrict__ O)
{
    int widx = threadIdx.x >> 6, lane = threadIdx.x & 63;
    int w = blockIdx.x * 4 + widx;
    int s = w / NH, h = w % NH;
    int qi = lane >> 3, kj = lane & 7;

    const ushort* qrow = qkv + (size_t)(s * 8 + qi) * (3 * DIM) + h * HD;
    const ushort* krow = qkv + (size_t)(s * 8 + kj) * (3 * DIM) + DIM + h * HD;
    float d = 0.f;
    #pragma unroll
    for (int c = 0; c < 8; ++c) {
        uint4 qa = *(const uint4*)(qrow + c * 8);
        uint4 ka = *(const uint4*)(krow + c * 8);
        const ushort* qs = (const ushort*)&qa;
        const ushort* ks = (const ushort*)&ka;
        #pragma unroll
        for (int e = 0; e < 8; ++e) d += bf2f(qs[e]) * bf2f(ks[e]);
    }
    float sc = d * 0.125f;
    float mx = sc;
    #pragma unroll
    for (int m = 4; m; m >>= 1) mx = fmaxf(mx, __shfl_xor(mx, m));
    float p = expf(sc - mx);
    float sum = p;
    #pragma unroll
    for (int m = 4; m; m >>= 1) sum += __shfl_xor(sum, m);
    p /= sum;

    float o[8] = {};
    int base = lane & ~7;
    #pragma unroll
    for (int t = 0; t < 8; ++t) {
        float pt = __shfl(p, base + t);
        const ushort* vrow = qkv + (size_t)(s * 8 + t) * (3 * DIM) + 2 * DIM + h * HD + kj * 8;
        uint4 va = *(const uint4*)vrow;
        const ushort* vs = (const ushort*)&va;
        #pragma unroll
        for (int e = 0; e < 8; ++e) o[e] += pt * bf2f(vs[e]);
    }
    ushort out[8];
    #pragma unroll
    for (int e = 0; e < 8; ++e) out[e] = f2bf(o[e]);
    *(uint4*)(O + (size_t)(s * 8 + qi) * DIM + h * HD + kj * 8) = *(const uint4*)out;
}

// ---------------------------------------------------------------------------
// Spatial attention, MFMA. One block per (s,h); 4 waves; 768 blocks.
// ---------------------------------------------------------------------------
#define KS_STRIDE 72
#define VT_STRIDE 208
#define P_STRIDE  208
#define KS_OFF    0
#define VT_OFF    (197 * KS_STRIDE)                 // 14184
#define P_OFF     (VT_OFF + 64 * VT_STRIDE)         // 27496
#define LDS_TOT   (P_OFF + 4 * 16 * P_STRIDE)       // 40808 ushorts = 79.7KB

__global__ __launch_bounds__(256, 2) void attn_spatial_mfma(
    const ushort* __restrict__ qkv, ushort* __restrict__ O)
{
    __shared__ ushort lds[LDS_TOT];
    const int tid = threadIdx.x, lane = tid & 63, wid = tid >> 6;
    const int fr = lane & 15, fq = lane >> 4;
    // XCD swizzle: the 12 heads of one sequence land on one XCD (shared qkv slab)
    int lin = xcd_lin(blockIdx.x, BT_ * NH);
    const int s = lin / NH, h = lin % NH;
    const size_t base = (size_t)s * NTOK * (3 * DIM);
    const ushort* Qg = qkv + base + h * HD;
    const ushort* Kg = qkv + base + DIM + h * HD;
    const ushort* Vg = qkv + base + 2 * DIM + h * HD;

    for (int chunk = tid; chunk < NTOK * 8; chunk += 256) {
        int r = chunk >> 3, c = (chunk & 7) * 8;
        uint4 v = *(const uint4*)(Kg + (size_t)r * (3 * DIM) + c);
        *(uint4*)&lds[KS_OFF + r * KS_STRIDE + c] = v;
    }
    for (int chunk = tid; chunk < 208 * 8; chunk += 256) {
        int k = chunk >> 3, c = (chunk & 7) * 8;
        uint4 v = {0u, 0u, 0u, 0u};
        if (k < NTOK) v = *(const uint4*)(Vg + (size_t)k * (3 * DIM) + c);
        const ushort* e = (const ushort*)&v;
        #pragma unroll
        for (int j = 0; j < 8; ++j) lds[VT_OFF + (c + j) * VT_STRIDE + k] = e[j];
    }
    __syncthreads();

    ushort* P = &lds[P_OFF + wid * 16 * P_STRIDE];

    for (int qi = wid; qi < 13; qi += 4) {
        int qrow = qi * 16 + fr; if (qrow > NTOK - 1) qrow = NTOK - 1;
        bf16x8 qf0 = *(const bf16x8*)(Qg + (size_t)qrow * (3 * DIM) + fq * 8);
        bf16x8 qf1 = *(const bf16x8*)(Qg + (size_t)qrow * (3 * DIM) + 32 + fq * 8);

        f32x4 sacc[13];
        #pragma unroll
        for (int t = 0; t < 13; ++t) {
            bf16x8 kf0 = *(const bf16x8*)&lds[KS_OFF + (t * 16 + fr) * KS_STRIDE + fq * 8];
            bf16x8 kf1 = *(const bf16x8*)&lds[KS_OFF + (t * 16 + fr) * KS_STRIDE + 32 + fq * 8];
            f32x4 z = {0.f, 0.f, 0.f, 0.f};
            z = __builtin_amdgcn_mfma_f32_16x16x32_bf16(kf0, qf0, z, 0, 0, 0);
            sacc[t] = __builtin_amdgcn_mfma_f32_16x16x32_bf16(kf1, qf1, z, 0, 0, 0);
        }

        float m = -1e30f;
        #pragma unroll
        for (int t = 0; t < 13; ++t)
            #pragma unroll
            for (int e = 0; e < 4; ++e) {
                int k = t * 16 + fq * 4 + e;
                float v = (k < NTOK) ? sacc[t][e] * 0.125f : -1e30f;
                sacc[t][e] = v;
                m = fmaxf(m, v);
            }
        m = fmaxf(m, __shfl_xor(m, 16));
        m = fmaxf(m, __shfl_xor(m, 32));
        float sum = 0.f;
        #pragma unroll
        for (int t = 0; t < 13; ++t)
            #pragma unroll
            for (int e = 0; e < 4; ++e) {
                float p = expf(sacc[t][e] - m);
                sacc[t][e] = p;
                sum += p;
            }
        sum += __shfl_xor(sum, 16);
        sum += __shfl_xor(sum, 32);
        float rd = 1.f / sum;

        #pragma unroll
        for (int t = 0; t < 13; ++t) {
            ushort2 w0 = { f2bf(sacc[t][0] * rd), f2bf(sacc[t][1] * rd) };
            ushort2 w1 = { f2bf(sacc[t][2] * rd), f2bf(sacc[t][3] * rd) };
            *(ushort2*)&P[fr * P_STRIDE + t * 16 + fq * 4]     = w0;
            *(ushort2*)&P[fr * P_STRIDE + t * 16 + fq * 4 + 2] = w1;
        }

        f32x4 oacc[4] = {};
        #pragma unroll
        for (int st = 0; st < 6; ++st) {
            bf16x8 pf = *(const bf16x8*)&P[fr * P_STRIDE + st * 32 + fq * 8];
            #pragma unroll
            for (int dt = 0; dt < 4; ++dt) {
                bf16x8 vf = *(const bf16x8*)&lds[VT_OFF + (dt * 16 + fr) * VT_STRIDE + st * 32 + fq * 8];
                oacc[dt] = __builtin_amdgcn_mfma_f32_16x16x32_bf16(pf, vf, oacc[dt], 0, 0, 0);
            }
        }
        {
            bf16x8 zz = {};
            bf16x8 pf = zz;
            if (fq < 2) pf = *(const bf16x8*)&P[fr * P_STRIDE + 192 + fq * 8];
            #pragma unroll
            for (int dt = 0; dt < 4; ++dt) {
                bf16x8 vf = zz;
                if (fq < 2) vf = *(const bf16x8*)&lds[VT_OFF + (dt * 16 + fr) * VT_STRIDE + 192 + fq * 8];
                oacc[dt] = __builtin_amdgcn_mfma_f32_16x16x32_bf16(pf, vf, oacc[dt], 0, 0, 0);
            }
        }

        #pragma unroll
        for (int dt = 0; dt < 4; ++dt)
            #pragma unroll
            for (int e = 0; e < 4; ++e) {
                int q = qi * 16 + fq * 4 + e;
                if (q < NTOK)
                    O[(size_t)(s * NTOK + q) * DIM + h * HD + dt * 16 + fr] = f2bf(oacc[dt][e]);
            }
    }
}

// ---------------------------------------------------------------------------
extern "C" void kernel_launch(void* const* d_in, const int* in_sizes, int n_in,
                              void* d_out, int out_size, void* d_ws, size_t ws_size,
                              hipStream_t stream)
{
    const float* x      = (const float*)d_in[0];
    const float* ln1_g  = (const float*)d_in[1];
    const float* ln1_b  = (const float*)d_in[2];
    const float* qkv_w  = (const float*)d_in[3];
    const float* proj_w = (const float*)d_in[4];
    const float* proj_b = (const float*)d_in[5];
    const float* tln_g  = (const float*)d_in[6];
    const float* tln_b  = (const float*)d_in[7];
    const float* tqkv_w = (const float*)d_in[8];
    const float* tproj_w= (const float*)d_in[9];
    const float* tproj_b= (const float*)d_in[10];
    const float* tfc_w  = (const float*)d_in[11];
    const float* tfc_b  = (const float*)d_in[12];
    const float* ln2_g  = (const float*)d_in[13];
    const float* ln2_b  = (const float*)d_in[14];
    const float* fc1_w  = (const float*)d_in[15];
    const float* fc1_b  = (const float*)d_in[16];
    const float* fc2_w  = (const float*)d_in[17];
    const float* fc2_b  = (const float*)d_in[18];

    float* out = (float*)d_out;   // fp32 residual accumulator = final output

    char* p = (char*)d_ws;
    ushort* w_qkv  = (ushort*)p; p += (size_t)(3*DIM*DIM) * 2;
    ushort* w_proj = (ushort*)p; p += (size_t)(DIM*DIM) * 2;
    ushort* w_tqkv = (ushort*)p; p += (size_t)(3*DIM*DIM) * 2;
    ushort* w_tproj= (ushort*)p; p += (size_t)(DIM*DIM) * 2;
    ushort* w_tfc  = (ushort*)p; p += (size_t)(DIM*DIM) * 2;
    ushort* w_fc1  = (ushort*)p; p += (size_t)(HID*DIM) * 2;
    ushort* w_fc2  = (ushort*)p; p += (size_t)(HID*DIM) * 2;
    ushort* bufA   = (ushort*)p; p += (size_t)MROWS * DIM * 2;
    ushort* bufC   = (ushort*)p; p += (size_t)MROWS * DIM * 2;
    ushort* bufB   = (ushort*)p;  // MROWS*3*DIM bf16

    auto castw = [&](const float* src, ushort* dst, int elems) {
        int n8 = elems / 8;
        cast_w<<<dim3((n8 + 255) / 256), dim3(256), 0, stream>>>(src, dst, n8);
    };
    castw(qkv_w,  w_qkv,  3*DIM*DIM);
    castw(proj_w, w_proj, DIM*DIM);
    castw(tqkv_w, w_tqkv, 3*DIM*DIM);
    castw(tproj_w,w_tproj,DIM*DIM);
    castw(tfc_w,  w_tfc,  DIM*DIM);
    castw(fc1_w,  w_fc1,  HID*DIM);
    castw(fc2_w,  w_fc2,  HID*DIM);

    {
        int n4 = MROWS * DIM / 4;
        copy_f32<<<dim3((n4 + 255) / 256), dim3(256), 0, stream>>>(x, out, n4);
    }

    // GEMM launcher: 1D grid nm*nn, grouped rasterization
    auto gemm = [&](auto tag, const ushort* A, const ushort* W, const float* bias,
                    ushort* C, float* xf, int M, int N, int K, int grp) {
        constexpr int E = decltype(tag)::value;
        int nm = (M + 127) / 128, nn = N / 128;
        gemm_bt<E><<<dim3(nm * nn), dim3(256), 0, stream>>>(
            A, W, bias, C, xf, M, N, K, nm, nn, grp);
    };
    using E0 = std::integral_constant<int, EPI_STORE>;
    using E1 = std::integral_constant<int, EPI_BIAS_STORE>;
    using E2 = std::integral_constant<int, EPI_BIAS_GELU>;
    using E3 = std::integral_constant<int, EPI_BIAS_ADD>;
    using E4 = std::integral_constant<int, EPI_BIAS_ADD_TFC>;

    // ---- temporal branch ----
    ln_gather<<<dim3(TROWS / 4), dim3(256), 0, stream>>>(x, tln_g, tln_b, bufA, TROWS);
    gemm(E0{}, bufA, w_tqkv, nullptr, bufB, nullptr, TROWS, 3 * DIM, DIM, 2);
    attn_temporal<<<dim3(TROWS * NH / 8 / 4), dim3(256), 0, stream>>>(bufB, bufC);
    gemm(E1{}, bufC, w_tproj, tproj_b, bufA, nullptr, TROWS, DIM, DIM, 8);
    gemm(E4{}, bufA, w_tfc, tfc_b, nullptr, out, TROWS, DIM, DIM, 8);

    // ---- spatial attention ----
    ln_f32<<<dim3((MROWS + 3) / 4), dim3(256), 0, stream>>>(out, ln1_g, ln1_b, bufA, MROWS);
    gemm(E0{}, bufA, w_qkv, nullptr, bufB, nullptr, MROWS, 3 * DIM, DIM, 2);
    attn_spatial_mfma<<<dim3(BT_ * NH), dim3(256), 0, stream>>>(bufB, bufC);
    gemm(E3{}, bufC, w_proj, proj_b, nullptr, out, MROWS, DIM, DIM, 8);

    // ---- MLP ----
    ln_f32<<<dim3((MROWS + 3) / 4), dim3(256), 0, stream>>>(out, ln2_g, ln2_b, bufA, MROWS);
    gemm(E2{}, bufA, w_fc1, fc1_b, bufB, nullptr, MROWS, HID, DIM, 8);
    gemm(E3{}, bufB, w_fc2, fc2_b, nullptr, out, MROWS, DIM, HID, 4);
}

// Round 5
// 424.360 us; speedup vs baseline: 5.7575x; 1.1764x over previous
//
#include <hip/hip_runtime.h>
#include <hip/hip_bf16.h>

// ---------------------------------------------------------------------------
// FactorizedAttentionBlock (TimeSformer divided space-time attention)
// DIM=768, NH=12, HD=64, HID=1152, B=8, T=8, HW=196, N=197, BT=64
// FP32 in/out. bf16 MFMA GEMMs + MFMA flash attention. fp32 residual in d_out.
// R5: GEMM rebuilt — compile-time K, BK=64, dbuf LDS, 2-phase counted-vmcnt
//     schedule, XOR-swizzled LDS (pre-swizzled global source). copy_f32
//     eliminated (tfc epilogue init + cls-row init); weight casts merged.
// ---------------------------------------------------------------------------

#define DIM   768
#define NH    12
#define HD    64
#define HID   1152
#define B_    8
#define T_    8
#define HW_   196
#define NTOK  197
#define BT_   64
#define MROWS (BT_ * NTOK)        // 12608
#define TROWS (B_ * HW_ * T_)     // 12544

typedef __bf16 bf16x8 __attribute__((ext_vector_type(8)));
typedef float  f32x4  __attribute__((ext_vector_type(4)));

__device__ inline float bf2f(ushort u) { return __uint_as_float(((unsigned)u) << 16); }
__device__ inline ushort f2bf(float f) {
    unsigned u = __float_as_uint(f);
    unsigned r = (u + 0x7fffu + ((u >> 16) & 1u)) >> 16;
    return (ushort)r;
}

__device__ inline float wred_sum(float v) {
    #pragma unroll
    for (int m = 32; m; m >>= 1) v += __shfl_xor(v, m);
    return v;
}

__device__ __forceinline__ void gload_lds16(const void* g, void* l) {
    __builtin_amdgcn_global_load_lds(
        (const __attribute__((address_space(1))) unsigned int*)g,
        (__attribute__((address_space(3))) unsigned int*)l, 16, 0, 0);
}

// XCD-bijective remap (m204)
__device__ __forceinline__ int xcd_lin(int gid, int nwg) {
    int q = nwg >> 3, r = nwg & 7;
    int xcd = gid & 7, idx = gid >> 3;
    return (xcd < r ? xcd * (q + 1) : r * (q + 1) + (xcd - r) * q) + idx;
}

// ---------------------------------------------------------------------------
// merged weight cast: 7 segments, block ranges by cumulative n8 counts
// ---------------------------------------------------------------------------
__global__ __launch_bounds__(256) void cast_all(
    const float* s0, ushort* d0, int c0, const float* s1, ushort* d1, int c1,
    const float* s2, ushort* d2, int c2, const float* s3, ushort* d3, int c3,
    const float* s4, ushort* d4, int c4, const float* s5, ushort* d5, int c5,
    const float* s6, ushort* d6, int c6)
{
    int i = blockIdx.x * 256 + threadIdx.x;
    const float* s; ushort* d; int base;
    if      (i < c0) { s = s0; d = d0; base = 0;  }
    else if (i < c1) { s = s1; d = d1; base = c0; }
    else if (i < c2) { s = s2; d = d2; base = c1; }
    else if (i < c3) { s = s3; d = d3; base = c2; }
    else if (i < c4) { s = s4; d = d4; base = c3; }
    else if (i < c5) { s = s5; d = d5; base = c4; }
    else if (i < c6) { s = s6; d = d6; base = c5; }
    else return;
    int k = i - base;
    float4 a = *(const float4*)(s + (size_t)k * 8);
    float4 b = *(const float4*)(s + (size_t)k * 8 + 4);
    ushort o[8] = {f2bf(a.x), f2bf(a.y), f2bf(a.z), f2bf(a.w),
                   f2bf(b.x), f2bf(b.y), f2bf(b.z), f2bf(b.w)};
    *(uint4*)(d + (size_t)k * 8) = *(const uint4*)o;
}

// init cls rows of out: out[s*197 + 0][:] = x[s*197 + 0][:]   (64 rows)
__global__ __launch_bounds__(256) void init_cls(const float* __restrict__ x, float* __restrict__ out)
{
    int i = blockIdx.x * 256 + threadIdx.x;     // 64 * 192 float4
    int r = i / 192, c = (i % 192) * 4;
    size_t off = ((size_t)r * NTOK) * DIM + c;
    *(float4*)(out + off) = *(const float4*)(x + off);
}

// ---------------------------------------------------------------------------
// GEMM: C[M,N] = A[M,K] @ W[N,K]^T (+bias)(+epi). 128x128 tile, 4 waves.
// BK=64, double-buffered LDS, 2-phase counted-vmcnt pipeline, XOR swizzle.
// K compile-time (768/1152). N multiple of 128; M may tail (row clamp).
// ---------------------------------------------------------------------------
enum { EPI_STORE = 0, EPI_BIAS_STORE = 1, EPI_BIAS_GELU = 2, EPI_BIAS_ADD = 3, EPI_BIAS_INIT_TFC = 4 };

template <int EPI, int KK>
__global__ __launch_bounds__(256) void gemm_bt(
    const ushort* __restrict__ Ag, const ushort* __restrict__ Wg,
    const float* __restrict__ bias, ushort* __restrict__ Cg,
    const float* __restrict__ xsrc, float* __restrict__ xf,
    int M, int N, int nm, int nn, int grp)
{
    __shared__ ushort As[2][128 * 64];   // 16KB each; rows of 128B
    __shared__ ushort Bs[2][128 * 64];

    const int tid  = threadIdx.x;
    const int lane = tid & 63, wid = tid >> 6;

    // grouped + XCD swizzle
    int lin = xcd_lin(blockIdx.x, nm * nn);
    int per = grp * nn;
    int g2 = lin / per, rem = lin % per;
    int bm = g2 * grp;
    int gm = nm - bm; if (gm > grp) gm = grp;
    const int m0 = (bm + rem % gm) * 128;
    const int n0 = (rem / gm) * 128;

    const int wm = (wid >> 1) * 64, wn = (wid & 1) * 64;
    const int fr = lane & 15, fq = lane >> 4;

    // staging: per K-step, 4 A-issues + 4 B-issues; issue j covers rows j*32..+31.
    // lane covers row j*32 + wid*8 + (lane>>3), source col swizzled by row&7.
    const int srow   = wid * 8 + (lane >> 3);
    const int scolsw = 8 * ((lane & 7) ^ (lane >> 3));    // pre-swizzled source col
    const ushort* aSrc[4]; const ushort* bSrc[4];
    #pragma unroll
    for (int j = 0; j < 4; ++j) {
        int ra = m0 + j * 32 + srow; if (ra >= M) ra = M - 1;
        aSrc[j] = Ag + (size_t)ra * KK + scolsw;
        bSrc[j] = Wg + (size_t)(n0 + j * 32 + srow) * KK + scolsw;
    }

    f32x4 acc[4][4] = {};

    auto STAGE = [&](int buf, int k0) {
        #pragma unroll
        for (int j = 0; j < 4; ++j) {
            gload_lds16(aSrc[j] + k0, &As[buf][(j * 32 + wid * 8) * 64]);
            gload_lds16(bSrc[j] + k0, &Bs[buf][(j * 32 + wid * 8) * 64]);
        }
    };

    auto COMPUTE = [&](int buf) {
        #pragma unroll
        for (int ks = 0; ks < 2; ++ks) {
            bf16x8 af[4], bfr[4];
            #pragma unroll
            for (int i = 0; i < 4; ++i)
                af[i] = *(const bf16x8*)&As[buf][(wm + i * 16 + fr) * 64 +
                                                ((ks * 32 + fq * 8) ^ ((fr & 7) * 8))];
            #pragma unroll
            for (int j = 0; j < 4; ++j)
                bfr[j] = *(const bf16x8*)&Bs[buf][(wn + j * 16 + fr) * 64 +
                                                 ((ks * 32 + fq * 8) ^ ((fr & 7) * 8))];
            #pragma unroll
            for (int i = 0; i < 4; ++i)
                #pragma unroll
                for (int j = 0; j < 4; ++j)
                    acc[i][j] = __builtin_amdgcn_mfma_f32_16x16x32_bf16(af[i], bfr[j], acc[i][j], 0, 0, 0);
        }
    };

    constexpr int NT = KK / 64;
    STAGE(0, 0);
    STAGE(1, 64);
    #pragma unroll
    for (int t = 0; t < NT; ++t) {
        // wait for own stage(t) loads (stage(t+1)'s 8 stay in flight)
        if (t + 2 < NT) asm volatile("s_waitcnt vmcnt(8)" ::: "memory");
        else if (t + 1 < NT) asm volatile("s_waitcnt vmcnt(8)" ::: "memory");
        else asm volatile("s_waitcnt vmcnt(0)" ::: "memory");
        __builtin_amdgcn_s_barrier();
        __builtin_amdgcn_sched_barrier(0);
        COMPUTE(t & 1);
        __builtin_amdgcn_sched_barrier(0);
        __builtin_amdgcn_s_barrier();          // all waves done reading buf[t&1]
        __builtin_amdgcn_sched_barrier(0);
        if (t + 2 < NT) STAGE(t & 1, (t + 2) * 64);
    }

    // D row = wm + i*16 + fq*4 + e, col = wn + j*16 + fr
    #pragma unroll
    for (int i = 0; i < 4; ++i) {
        #pragma unroll
        for (int e = 0; e < 4; ++e) {
            int row = m0 + wm + i * 16 + fq * 4 + e;
            if (row >= M) continue;
            #pragma unroll
            for (int j = 0; j < 4; ++j) {
                int col = n0 + wn + j * 16 + fr;
                float v = acc[i][j][e];
                if constexpr (EPI != EPI_STORE) v += bias[col];
                if constexpr (EPI == EPI_BIAS_GELU) v = 0.5f * v * (1.0f + erff(v * 0.70710678118654752f));
                if constexpr (EPI == EPI_STORE || EPI == EPI_BIAS_STORE || EPI == EPI_BIAS_GELU) {
                    Cg[(size_t)row * N + col] = f2bf(v);
                } else if constexpr (EPI == EPI_BIAS_ADD) {
                    xf[(size_t)row * DIM + col] += v;
                } else {  // EPI_BIAS_INIT_TFC: out = x + v, row remap
                    int t2 = row & 7, pp = (row >> 3) % HW_, bb = row / (HW_ * T_);
                    size_t dst = ((size_t)(bb * T_ + t2) * NTOK + 1 + pp) * DIM + col;
                    xf[dst] = xsrc[dst] + v;
                }
            }
        }
    }
}

// ---------------------------------------------------------------------------
// LayerNorm fp32 src -> bf16 dst (768 wide, 1 wave/row)
// ---------------------------------------------------------------------------
__global__ __launch_bounds__(256) void ln_f32(
    const float* __restrict__ src, const float* __restrict__ g,
    const float* __restrict__ b, ushort* __restrict__ dst, int rows)
{
    int widx = threadIdx.x >> 6, lane = threadIdx.x & 63;
    int r = blockIdx.x * 4 + widx;
    if (r >= rows) return;
    const float* row = src + (size_t)r * DIM;
    float v[12], sum = 0.f, sq = 0.f;
    #pragma unroll
    for (int c = 0; c < 3; ++c) {
        float4 t = *(const float4*)(row + c * 256 + lane * 4);
        v[c*4+0] = t.x; v[c*4+1] = t.y; v[c*4+2] = t.z; v[c*4+3] = t.w;
        sum += t.x + t.y + t.z + t.w;
        sq  += t.x*t.x + t.y*t.y + t.z*t.z + t.w*t.w;
    }
    sum = wred_sum(sum); sq = wred_sum(sq);
    float mean = sum * (1.f / DIM);
    float var  = sq * (1.f / DIM) - mean * mean;
    float rstd = rsqrtf(var + 1e-5f);
    #pragma unroll
    for (int c = 0; c < 3; ++c) {
        int idx = c * 256 + lane * 4;
        float4 gg = *(const float4*)(g + idx);
        float4 bb = *(const float4*)(b + idx);
        ushort4 o;
        o.x = f2bf((v[c*4+0] - mean) * rstd * gg.x + bb.x);
        o.y = f2bf((v[c*4+1] - mean) * rstd * gg.y + bb.y);
        o.z = f2bf((v[c*4+2] - mean) * rstd * gg.z + bb.z);
        o.w = f2bf((v[c*4+3] - mean) * rstd * gg.w + bb.w);
        *(ushort4*)(dst + (size_t)r * DIM + idx) = o;
    }
}

// Temporal gather + LN: out row r=(b*196+p)*8+t  <-  x[(b*8+t)][1+p][:]
__global__ __launch_bounds__(256) void ln_gather(
    const float* __restrict__ x, const float* __restrict__ g,
    const float* __restrict__ b, ushort* __restrict__ dst, int rows)
{
    int widx = threadIdx.x >> 6, lane = threadIdx.x & 63;
    int r = blockIdx.x * 4 + widx;
    if (r >= rows) return;
    int t = r & 7, pp = (r >> 3) % HW_, bb = r / (HW_ * T_);
    const float* row = x + ((size_t)(bb * T_ + t) * NTOK + 1 + pp) * DIM;
    float v[12], sum = 0.f, sq = 0.f;
    #pragma unroll
    for (int c = 0; c < 3; ++c) {
        float4 t4 = *(const float4*)(row + c * 256 + lane * 4);
        v[c*4+0] = t4.x; v[c*4+1] = t4.y; v[c*4+2] = t4.z; v[c*4+3] = t4.w;
        sum += t4.x + t4.y + t4.z + t4.w;
        sq  += t4.x*t4.x + t4.y*t4.y + t4.z*t4.z + t4.w*t4.w;
    }
    sum = wred_sum(sum); sq = wred_sum(sq);
    float mean = sum * (1.f / DIM);
    float var  = sq * (1.f / DIM) - mean * mean;
    float rstd = rsqrtf(var + 1e-5f);
    #pragma unroll
    for (int c = 0; c < 3; ++c) {
        int idx = c * 256 + lane * 4;
        float4 gg = *(const float4*)(g + idx);
        float4 bb2 = *(const float4*)(b + idx);
        ushort4 o;
        o.x = f2bf((v[c*4+0] - mean) * rstd * gg.x + bb2.x);
        o.y = f2bf((v[c*4+1] - mean) * rstd * gg.y + bb2.y);
        o.z = f2bf((v[c*4+2] - mean) * rstd * gg.z + bb2.z);
        o.w = f2bf((v[c*4+3] - mean) * rstd * gg.w + bb2.w);
        *(ushort4*)(dst + (size_t)r * DIM + idx) = o;
    }
}

// ---------------------------------------------------------------------------
// Temporal attention: seq len 8, one wave per (seq, head); lane=(qi*8+kj)
// ---------------------------------------------------------------------------
__global__ __launch_bounds__(256) void attn_temporal(
    const ushort* __restrict__ qkv, ushort* __restrict__ O)
{
    int widx = threadIdx.x >> 6, lane = threadIdx.x & 63;
    int w = blockIdx.x * 4 + widx;
    int s = w / NH, h = w % NH;
    int qi = lane >> 3, kj = lane & 7;

    const ushort* qrow = qkv + (size_t)(s * 8 + qi) * (3 * DIM) + h * HD;
    const ushort* krow = qkv + (size_t)(s * 8 + kj) * (3 * DIM) + DIM + h * HD;
    float d = 0.f;
    #pragma unroll
    for (int c = 0; c < 8; ++c) {
        uint4 qa = *(const uint4*)(qrow + c * 8);
        uint4 ka = *(const uint4*)(krow + c * 8);
        const ushort* qs = (const ushort*)&qa;
        const ushort* ks = (const ushort*)&ka;
        #pragma unroll
        for (int e = 0; e < 8; ++e) d += bf2f(qs[e]) * bf2f(ks[e]);
    }
    float sc = d * 0.125f;
    float mx = sc;
    #pragma unroll
    for (int m = 4; m; m >>= 1) mx = fmaxf(mx, __shfl_xor(mx, m));
    float p = expf(sc - mx);
    float sum = p;
    #pragma unroll
    for (int m = 4; m; m >>= 1) sum += __shfl_xor(sum, m);
    p /= sum;

    float o[8] = {};
    int base = lane & ~7;
    #pragma unroll
    for (int t = 0; t < 8; ++t) {
        float pt = __shfl(p, base + t);
        const ushort* vrow = qkv + (size_t)(s * 8 + t) * (3 * DIM) + 2 * DIM + h * HD + kj * 8;
        uint4 va = *(const uint4*)vrow;
        const ushort* vs = (const ushort*)&va;
        #pragma unroll
        for (int e = 0; e < 8; ++e) o[e] += pt * bf2f(vs[e]);
    }
    ushort out[8];
    #pragma unroll
    for (int e = 0; e < 8; ++e) out[e] = f2bf(o[e]);
    *(uint4*)(O + (size_t)(s * 8 + qi) * DIM + h * HD + kj * 8) = *(const uint4*)out;
}

// ---------------------------------------------------------------------------
// Spatial attention, MFMA. One block per (s,h); 4 waves; 768 blocks.
// ---------------------------------------------------------------------------
#define KS_STRIDE 72
#define VT_STRIDE 208
#define P_STRIDE  208
#define KS_OFF    0
#define VT_OFF    (197 * KS_STRIDE)
#define P_OFF     (VT_OFF + 64 * VT_STRIDE)
#define LDS_TOT   (P_OFF + 4 * 16 * P_STRIDE)

__global__ __launch_bounds__(256, 2) void attn_spatial_mfma(
    const ushort* __restrict__ qkv, ushort* __restrict__ O)
{
    __shared__ ushort lds[LDS_TOT];
    const int tid = threadIdx.x, lane = tid & 63, wid = tid >> 6;
    const int fr = lane & 15, fq = lane >> 4;
    int lin = xcd_lin(blockIdx.x, BT_ * NH);
    const int s = lin / NH, h = lin % NH;
    const size_t base = (size_t)s * NTOK * (3 * DIM);
    const ushort* Qg = qkv + base + h * HD;
    const ushort* Kg = qkv + base + DIM + h * HD;
    const ushort* Vg = qkv + base + 2 * DIM + h * HD;

    for (int chunk = tid; chunk < NTOK * 8; chunk += 256) {
        int r = chunk >> 3, c = (chunk & 7) * 8;
        uint4 v = *(const uint4*)(Kg + (size_t)r * (3 * DIM) + c);
        *(uint4*)&lds[KS_OFF + r * KS_STRIDE + c] = v;
    }
    for (int chunk = tid; chunk < 208 * 8; chunk += 256) {
        int k = chunk >> 3, c = (chunk & 7) * 8;
        uint4 v = {0u, 0u, 0u, 0u};
        if (k < NTOK) v = *(const uint4*)(Vg + (size_t)k * (3 * DIM) + c);
        const ushort* e = (const ushort*)&v;
        #pragma unroll
        for (int j = 0; j < 8; ++j) lds[VT_OFF + (c + j) * VT_STRIDE + k] = e[j];
    }
    __syncthreads();

    ushort* P = &lds[P_OFF + wid * 16 * P_STRIDE];

    for (int qi = wid; qi < 13; qi += 4) {
        int qrow = qi * 16 + fr; if (qrow > NTOK - 1) qrow = NTOK - 1;
        bf16x8 qf0 = *(const bf16x8*)(Qg + (size_t)qrow * (3 * DIM) + fq * 8);
        bf16x8 qf1 = *(const bf16x8*)(Qg + (size_t)qrow * (3 * DIM) + 32 + fq * 8);

        f32x4 sacc[13];
        #pragma unroll
        for (int t = 0; t < 13; ++t) {
            bf16x8 kf0 = *(const bf16x8*)&lds[KS_OFF + (t * 16 + fr) * KS_STRIDE + fq * 8];
            bf16x8 kf1 = *(const bf16x8*)&lds[KS_OFF + (t * 16 + fr) * KS_STRIDE + 32 + fq * 8];
            f32x4 z = {0.f, 0.f, 0.f, 0.f};
            z = __builtin_amdgcn_mfma_f32_16x16x32_bf16(kf0, qf0, z, 0, 0, 0);
            sacc[t] = __builtin_amdgcn_mfma_f32_16x16x32_bf16(kf1, qf1, z, 0, 0, 0);
        }

        float m = -1e30f;
        #pragma unroll
        for (int t = 0; t < 13; ++t)
            #pragma unroll
            for (int e = 0; e < 4; ++e) {
                int k = t * 16 + fq * 4 + e;
                float v = (k < NTOK) ? sacc[t][e] * 0.125f : -1e30f;
                sacc[t][e] = v;
                m = fmaxf(m, v);
            }
        m = fmaxf(m, __shfl_xor(m, 16));
        m = fmaxf(m, __shfl_xor(m, 32));
        float sum = 0.f;
        #pragma unroll
        for (int t = 0; t < 13; ++t)
            #pragma unroll
            for (int e = 0; e < 4; ++e) {
                float p = expf(sacc[t][e] - m);
                sacc[t][e] = p;
                sum += p;
            }
        sum += __shfl_xor(sum, 16);
        sum += __shfl_xor(sum, 32);
        float rd = 1.f / sum;

        #pragma unroll
        for (int t = 0; t < 13; ++t) {
            ushort2 w0 = { f2bf(sacc[t][0] * rd), f2bf(sacc[t][1] * rd) };
            ushort2 w1 = { f2bf(sacc[t][2] * rd), f2bf(sacc[t][3] * rd) };
            *(ushort2*)&P[fr * P_STRIDE + t * 16 + fq * 4]     = w0;
            *(ushort2*)&P[fr * P_STRIDE + t * 16 + fq * 4 + 2] = w1;
        }

        f32x4 oacc[4] = {};
        #pragma unroll
        for (int st = 0; st < 6; ++st) {
            bf16x8 pf = *(const bf16x8*)&P[fr * P_STRIDE + st * 32 + fq * 8];
            #pragma unroll
            for (int dt = 0; dt < 4; ++dt) {
                bf16x8 vf = *(const bf16x8*)&lds[VT_OFF + (dt * 16 + fr) * VT_STRIDE + st * 32 + fq * 8];
                oacc[dt] = __builtin_amdgcn_mfma_f32_16x16x32_bf16(pf, vf, oacc[dt], 0, 0, 0);
            }
        }
        {
            bf16x8 zz = {};
            bf16x8 pf = zz;
            if (fq < 2) pf = *(const bf16x8*)&P[fr * P_STRIDE + 192 + fq * 8];
            #pragma unroll
            for (int dt = 0; dt < 4; ++dt) {
                bf16x8 vf = zz;
                if (fq < 2) vf = *(const bf16x8*)&lds[VT_OFF + (dt * 16 + fr) * VT_STRIDE + 192 + fq * 8];
                oacc[dt] = __builtin_amdgcn_mfma_f32_16x16x32_bf16(pf, vf, oacc[dt], 0, 0, 0);
            }
        }

        #pragma unroll
        for (int dt = 0; dt < 4; ++dt)
            #pragma unroll
            for (int e = 0; e < 4; ++e) {
                int q = qi * 16 + fq * 4 + e;
                if (q < NTOK)
                    O[(size_t)(s * NTOK + q) * DIM + h * HD + dt * 16 + fr] = f2bf(oacc[dt][e]);
            }
    }
}

// ---------------------------------------------------------------------------
extern "C" void kernel_launch(void* const* d_in, const int* in_sizes, int n_in,
                              void* d_out, int out_size, void* d_ws, size_t ws_size,
                              hipStream_t stream)
{
    const float* x      = (const float*)d_in[0];
    const float* ln1_g  = (const float*)d_in[1];
    const float* ln1_b  = (const float*)d_in[2];
    const float* qkv_w  = (const float*)d_in[3];
    const float* proj_w = (const float*)d_in[4];
    const float* proj_b = (const float*)d_in[5];
    const float* tln_g  = (const float*)d_in[6];
    const float* tln_b  = (const float*)d_in[7];
    const float* tqkv_w = (const float*)d_in[8];
    const float* tproj_w= (const float*)d_in[9];
    const float* tproj_b= (const float*)d_in[10];
    const float* tfc_w  = (const float*)d_in[11];
    const float* tfc_b  = (const float*)d_in[12];
    const float* ln2_g  = (const float*)d_in[13];
    const float* ln2_b  = (const float*)d_in[14];
    const float* fc1_w  = (const float*)d_in[15];
    const float* fc1_b  = (const float*)d_in[16];
    const float* fc2_w  = (const float*)d_in[17];
    const float* fc2_b  = (const float*)d_in[18];

    float* out = (float*)d_out;   // fp32 residual accumulator = final output

    char* p = (char*)d_ws;
    ushort* w_qkv  = (ushort*)p; p += (size_t)(3*DIM*DIM) * 2;
    ushort* w_proj = (ushort*)p; p += (size_t)(DIM*DIM) * 2;
    ushort* w_tqkv = (ushort*)p; p += (size_t)(3*DIM*DIM) * 2;
    ushort* w_tproj= (ushort*)p; p += (size_t)(DIM*DIM) * 2;
    ushort* w_tfc  = (ushort*)p; p += (size_t)(DIM*DIM) * 2;
    ushort* w_fc1  = (ushort*)p; p += (size_t)(HID*DIM) * 2;
    ushort* w_fc2  = (ushort*)p; p += (size_t)(HID*DIM) * 2;
    ushort* bufA   = (ushort*)p; p += (size_t)MROWS * DIM * 2;
    ushort* bufC   = (ushort*)p; p += (size_t)MROWS * DIM * 2;
    ushort* bufB   = (ushort*)p;  // MROWS*3*DIM bf16

    // merged weight casts (cumulative n8 ends)
    {
        const int DD8 = DIM * DIM / 8;            // 73728
        int c0 = 3 * DD8;                         // qkv
        int c1 = c0 + DD8;                        // proj
        int c2 = c1 + 3 * DD8;                    // tqkv
        int c3 = c2 + DD8;                        // tproj
        int c4 = c3 + DD8;                        // tfc
        int c5 = c4 + HID * DIM / 8;              // fc1
        int c6 = c5 + HID * DIM / 8;              // fc2
        cast_all<<<dim3((c6 + 255) / 256), dim3(256), 0, stream>>>(
            qkv_w, w_qkv, c0, proj_w, w_proj, c1, tqkv_w, w_tqkv, c2,
            tproj_w, w_tproj, c3, tfc_w, w_tfc, c4, fc1_w, w_fc1, c5,
            fc2_w, w_fc2, c6);
    }

    // init cls rows of out (non-cls rows written by tfc epilogue)
    init_cls<<<dim3(48), dim3(256), 0, stream>>>(x, out);

    auto grid = [](int M, int N) { return dim3(((M + 127) / 128) * (N / 128)); };
    #define GEMM(EPI, KV, A, W, BIAS, C, XS, XF, M, N, GRP) \
        gemm_bt<EPI, KV><<<grid(M, N), dim3(256), 0, stream>>>( \
            A, W, BIAS, C, XS, XF, M, N, (M + 127) / 128, (N) / 128, GRP)

    // ---- temporal branch ----
    ln_gather<<<dim3(TROWS / 4), dim3(256), 0, stream>>>(x, tln_g, tln_b, bufA, TROWS);
    GEMM(EPI_STORE, DIM, bufA, w_tqkv, nullptr, bufB, nullptr, nullptr, TROWS, 3 * DIM, 2);
    attn_temporal<<<dim3(TROWS * NH / 8 / 4), dim3(256), 0, stream>>>(bufB, bufC);
    GEMM(EPI_BIAS_STORE, DIM, bufC, w_tproj, tproj_b, bufA, nullptr, nullptr, TROWS, DIM, 8);
    GEMM(EPI_BIAS_INIT_TFC, DIM, bufA, w_tfc, tfc_b, nullptr, x, out, TROWS, DIM, 8);

    // ---- spatial attention ----
    ln_f32<<<dim3((MROWS + 3) / 4), dim3(256), 0, stream>>>(out, ln1_g, ln1_b, bufA, MROWS);
    GEMM(EPI_STORE, DIM, bufA, w_qkv, nullptr, bufB, nullptr, nullptr, MROWS, 3 * DIM, 2);
    attn_spatial_mfma<<<dim3(BT_ * NH), dim3(256), 0, stream>>>(bufB, bufC);
    GEMM(EPI_BIAS_ADD, DIM, bufC, w_proj, proj_b, nullptr, nullptr, out, MROWS, DIM, 8);

    // ---- MLP ----
    ln_f32<<<dim3((MROWS + 3) / 4), dim3(256), 0, stream>>>(out, ln2_g, ln2_b, bufA, MROWS);
    GEMM(EPI_BIAS_GELU, DIM, bufA, w_fc1, fc1_b, bufB, nullptr, nullptr, MROWS, HID, 8);
    GEMM(EPI_BIAS_ADD, HID, bufB, w_fc2, fc2_b, nullptr, nullptr, out, MROWS, DIM, 4);
    #undef GEMM
}

// Round 6
// 415.523 us; speedup vs baseline: 5.8799x; 1.0213x over previous
//
#include <hip/hip_runtime.h>
#include <hip/hip_bf16.h>

// ---------------------------------------------------------------------------
// FactorizedAttentionBlock (TimeSformer divided space-time attention)
// DIM=768, NH=12, HD=64, HID=1152, B=8, T=8, HW=196, N=197, BT=64
// FP32 in/out. bf16 MFMA GEMMs + MFMA flash attention. fp32 residual in d_out.
// R6: qkv GEMMs -> 256x256 8-wave phase-split kernel (T3/T4/T5 style):
//     4 phases/K-tile, 16 MFMA/phase, stage spread over phases 0-1,
//     one vmcnt(0)+barrier per K-tile, setprio around MFMA clusters.
// ---------------------------------------------------------------------------

#define DIM   768
#define NH    12
#define HD    64
#define HID   1152
#define B_    8
#define T_    8
#define HW_   196
#define NTOK  197
#define BT_   64
#define MROWS (BT_ * NTOK)        // 12608
#define TROWS (B_ * HW_ * T_)     // 12544

typedef __bf16 bf16x8 __attribute__((ext_vector_type(8)));
typedef float  f32x4  __attribute__((ext_vector_type(4)));

__device__ inline float bf2f(ushort u) { return __uint_as_float(((unsigned)u) << 16); }
__device__ inline ushort f2bf(float f) {
    unsigned u = __float_as_uint(f);
    unsigned r = (u + 0x7fffu + ((u >> 16) & 1u)) >> 16;
    return (ushort)r;
}

__device__ inline float wred_sum(float v) {
    #pragma unroll
    for (int m = 32; m; m >>= 1) v += __shfl_xor(v, m);
    return v;
}

__device__ __forceinline__ void gload_lds16(const void* g, void* l) {
    __builtin_amdgcn_global_load_lds(
        (const __attribute__((address_space(1))) unsigned int*)g,
        (__attribute__((address_space(3))) unsigned int*)l, 16, 0, 0);
}

// XCD-bijective remap (m204)
__device__ __forceinline__ int xcd_lin(int gid, int nwg) {
    int q = nwg >> 3, r = nwg & 7;
    int xcd = gid & 7, idx = gid >> 3;
    return (xcd < r ? xcd * (q + 1) : r * (q + 1) + (xcd - r) * q) + idx;
}

#define MFMA16(a, b, c) __builtin_amdgcn_mfma_f32_16x16x32_bf16(a, b, c, 0, 0, 0)

// ---------------------------------------------------------------------------
// merged weight cast
// ---------------------------------------------------------------------------
__global__ __launch_bounds__(256) void cast_all(
    const float* s0, ushort* d0, int c0, const float* s1, ushort* d1, int c1,
    const float* s2, ushort* d2, int c2, const float* s3, ushort* d3, int c3,
    const float* s4, ushort* d4, int c4, const float* s5, ushort* d5, int c5,
    const float* s6, ushort* d6, int c6)
{
    int i = blockIdx.x * 256 + threadIdx.x;
    const float* s; ushort* d; int base;
    if      (i < c0) { s = s0; d = d0; base = 0;  }
    else if (i < c1) { s = s1; d = d1; base = c0; }
    else if (i < c2) { s = s2; d = d2; base = c1; }
    else if (i < c3) { s = s3; d = d3; base = c2; }
    else if (i < c4) { s = s4; d = d4; base = c3; }
    else if (i < c5) { s = s5; d = d5; base = c4; }
    else if (i < c6) { s = s6; d = d6; base = c5; }
    else return;
    int k = i - base;
    float4 a = *(const float4*)(s + (size_t)k * 8);
    float4 b = *(const float4*)(s + (size_t)k * 8 + 4);
    ushort o[8] = {f2bf(a.x), f2bf(a.y), f2bf(a.z), f2bf(a.w),
                   f2bf(b.x), f2bf(b.y), f2bf(b.z), f2bf(b.w)};
    *(uint4*)(d + (size_t)k * 8) = *(const uint4*)o;
}

// init cls rows of out: out[s*197 + 0][:] = x[s*197 + 0][:]   (64 rows)
__global__ __launch_bounds__(256) void init_cls(const float* __restrict__ x, float* __restrict__ out)
{
    int i = blockIdx.x * 256 + threadIdx.x;     // 64 * 192 float4
    int r = i / 192, c = (i % 192) * 4;
    size_t off = ((size_t)r * NTOK) * DIM + c;
    *(float4*)(out + off) = *(const float4*)(x + off);
}

// ---------------------------------------------------------------------------
// gemm256: C[M,N] = A[M,K] @ W[N,K]^T, bf16 out. 256x256 tile, 8 waves (2Mx4N),
// per-wave 128x64. BK=64, dbuf LDS (128KB), 4 phases/K-tile:
//   P0: read A[qm0](8)+B[qn0](4), stage A(t+1);  MFMA quad(0,0)
//   P1: read B[qn1](4),           stage B(t+1);  MFMA quad(0,1)
//   P2: read A[qm1](8);                          MFMA quad(1,0)
//   P3:                                          MFMA quad(1,1)
// One vmcnt(0)+s_barrier per K-tile. XOR-swizzled LDS via pre-swizzled source.
// ---------------------------------------------------------------------------
template <int KK>
__global__ __launch_bounds__(512, 1) void gemm256(
    const ushort* __restrict__ Ag, const ushort* __restrict__ Wg,
    ushort* __restrict__ Cg, int M, int N, int nm, int nn, int grp)
{
    __shared__ ushort As[2][256 * 64];   // 32KB per buf
    __shared__ ushort Bs[2][256 * 64];

    const int tid  = threadIdx.x;
    const int lane = tid & 63, wid = tid >> 6;
    const int wr = wid >> 2, wc = wid & 3;
    const int fr = lane & 15, fq = lane >> 4;

    int lin = xcd_lin(blockIdx.x, nm * nn);
    int per = grp * nn;
    int g2 = lin / per, rem = lin % per;
    int bm = g2 * grp;
    int gm = nm - bm; if (gm > grp) gm = grp;
    const int m0 = (bm + rem % gm) * 256;
    const int n0 = (rem / gm) * 256;

    // staging: issue j covers rows j*64 + wid*8 + (lane>>3); chunk pos lane&7
    const int srow = wid * 8 + (lane >> 3);
    const int scol = 8 * ((lane & 7) ^ (lane >> 3));   // pre-swizzled source col
    const ushort* aP[4]; const ushort* bP[4];
    #pragma unroll
    for (int j = 0; j < 4; ++j) {
        int ra = m0 + j * 64 + srow; if (ra >= M) ra = M - 1;
        aP[j] = Ag + (size_t)ra * KK + scol;
        bP[j] = Wg + (size_t)(n0 + j * 64 + srow) * KK + scol;
    }
    const int ldso = (wid * 8) * 64;   // wave slab base (elems)

    f32x4 acc[8][4] = {};
    bf16x8 af[4][2], b0[2][2], b1[2][2];

    const int sw0 = (fq * 8) ^ ((fr & 7) * 8);
    const int sw1 = (32 + fq * 8) ^ ((fr & 7) * 8);

    // prologue: stage tile 0
    #pragma unroll
    for (int j = 0; j < 4; ++j) gload_lds16(aP[j], &As[0][j * 4096 + ldso]);
    #pragma unroll
    for (int j = 0; j < 4; ++j) gload_lds16(bP[j], &Bs[0][j * 4096 + ldso]);

    constexpr int NT = KK / 64;
    #pragma unroll
    for (int t = 0; t < NT; ++t) {
        const int rb = t & 1, wb = rb ^ 1;
        const bool st = (t + 1 < NT);
        const int kw = (t + 1) * 64;

        asm volatile("s_waitcnt vmcnt(0)" ::: "memory");
        __builtin_amdgcn_s_barrier();
        __builtin_amdgcn_sched_barrier(0);

        // ---- phase 0 ----
        #pragma unroll
        for (int mf = 0; mf < 4; ++mf) {
            af[mf][0] = *(const bf16x8*)&As[rb][(wr * 128 + mf * 16 + fr) * 64 + sw0];
            af[mf][1] = *(const bf16x8*)&As[rb][(wr * 128 + mf * 16 + fr) * 64 + sw1];
        }
        #pragma unroll
        for (int nf = 0; nf < 2; ++nf) {
            b0[nf][0] = *(const bf16x8*)&Bs[rb][(wc * 64 + nf * 16 + fr) * 64 + sw0];
            b0[nf][1] = *(const bf16x8*)&Bs[rb][(wc * 64 + nf * 16 + fr) * 64 + sw1];
        }
        if (st) {
            #pragma unroll
            for (int j = 0; j < 4; ++j) gload_lds16(aP[j] + kw, &As[wb][j * 4096 + ldso]);
        }
        asm volatile("s_waitcnt lgkmcnt(0)" ::: "memory");
        __builtin_amdgcn_sched_barrier(0);
        __builtin_amdgcn_s_setprio(1);
        #pragma unroll
        for (int mf = 0; mf < 4; ++mf)
            #pragma unroll
            for (int nf = 0; nf < 2; ++nf) {
                acc[mf][nf] = MFMA16(af[mf][0], b0[nf][0], acc[mf][nf]);
                acc[mf][nf] = MFMA16(af[mf][1], b0[nf][1], acc[mf][nf]);
            }
        __builtin_amdgcn_s_setprio(0);
        __builtin_amdgcn_sched_barrier(0);

        // ---- phase 1 ----
        #pragma unroll
        for (int nf = 0; nf < 2; ++nf) {
            b1[nf][0] = *(const bf16x8*)&Bs[rb][(wc * 64 + (nf + 2) * 16 + fr) * 64 + sw0];
            b1[nf][1] = *(const bf16x8*)&Bs[rb][(wc * 64 + (nf + 2) * 16 + fr) * 64 + sw1];
        }
        if (st) {
            #pragma unroll
            for (int j = 0; j < 4; ++j) gload_lds16(bP[j] + kw, &Bs[wb][j * 4096 + ldso]);
        }
        asm volatile("s_waitcnt lgkmcnt(0)" ::: "memory");
        __builtin_amdgcn_sched_barrier(0);
        __builtin_amdgcn_s_setprio(1);
        #pragma unroll
        for (int mf = 0; mf < 4; ++mf)
            #pragma unroll
            for (int nf = 0; nf < 2; ++nf) {
                acc[mf][nf + 2] = MFMA16(af[mf][0], b1[nf][0], acc[mf][nf + 2]);
                acc[mf][nf + 2] = MFMA16(af[mf][1], b1[nf][1], acc[mf][nf + 2]);
            }
        __builtin_amdgcn_s_setprio(0);
        __builtin_amdgcn_sched_barrier(0);

        // ---- phase 2 ----
        #pragma unroll
        for (int mf = 0; mf < 4; ++mf) {
            af[mf][0] = *(const bf16x8*)&As[rb][(wr * 128 + 64 + mf * 16 + fr) * 64 + sw0];
            af[mf][1] = *(const bf16x8*)&As[rb][(wr * 128 + 64 + mf * 16 + fr) * 64 + sw1];
        }
        asm volatile("s_waitcnt lgkmcnt(0)" ::: "memory");
        __builtin_amdgcn_sched_barrier(0);
        __builtin_amdgcn_s_setprio(1);
        #pragma unroll
        for (int mf = 0; mf < 4; ++mf)
            #pragma unroll
            for (int nf = 0; nf < 2; ++nf) {
                acc[mf + 4][nf] = MFMA16(af[mf][0], b0[nf][0], acc[mf + 4][nf]);
                acc[mf + 4][nf] = MFMA16(af[mf][1], b0[nf][1], acc[mf + 4][nf]);
            }
        __builtin_amdgcn_s_setprio(0);
        __builtin_amdgcn_sched_barrier(0);

        // ---- phase 3 ----
        __builtin_amdgcn_s_setprio(1);
        #pragma unroll
        for (int mf = 0; mf < 4; ++mf)
            #pragma unroll
            for (int nf = 0; nf < 2; ++nf) {
                acc[mf + 4][nf + 2] = MFMA16(af[mf][0], b1[nf][0], acc[mf + 4][nf + 2]);
                acc[mf + 4][nf + 2] = MFMA16(af[mf][1], b1[nf][1], acc[mf + 4][nf + 2]);
            }
        __builtin_amdgcn_s_setprio(0);
        __builtin_amdgcn_sched_barrier(0);
    }

    // epilogue: row = m0 + wr*128 + mf*16 + fq*4 + e; col = n0 + wc*64 + nf*16 + fr
    #pragma unroll
    for (int mf = 0; mf < 8; ++mf)
        #pragma unroll
        for (int e = 0; e < 4; ++e) {
            int row = m0 + wr * 128 + mf * 16 + fq * 4 + e;
            if (row >= M) continue;
            #pragma unroll
            for (int nf = 0; nf < 4; ++nf)
                Cg[(size_t)row * N + n0 + wc * 64 + nf * 16 + fr] = f2bf(acc[mf][nf][e]);
        }
}

// ---------------------------------------------------------------------------
// GEMM 128x128 (R5 structure): used for N=768/1152 GEMMs.
// ---------------------------------------------------------------------------
enum { EPI_STORE = 0, EPI_BIAS_STORE = 1, EPI_BIAS_GELU = 2, EPI_BIAS_ADD = 3, EPI_BIAS_INIT_TFC = 4 };

template <int EPI, int KK>
__global__ __launch_bounds__(256) void gemm_bt(
    const ushort* __restrict__ Ag, const ushort* __restrict__ Wg,
    const float* __restrict__ bias, ushort* __restrict__ Cg,
    const float* __restrict__ xsrc, float* __restrict__ xf,
    int M, int N, int nm, int nn, int grp)
{
    __shared__ ushort As[2][128 * 64];
    __shared__ ushort Bs[2][128 * 64];

    const int tid  = threadIdx.x;
    const int lane = tid & 63, wid = tid >> 6;

    int lin = xcd_lin(blockIdx.x, nm * nn);
    int per = grp * nn;
    int g2 = lin / per, rem = lin % per;
    int bm = g2 * grp;
    int gm = nm - bm; if (gm > grp) gm = grp;
    const int m0 = (bm + rem % gm) * 128;
    const int n0 = (rem / gm) * 128;

    const int wm = (wid >> 1) * 64, wn = (wid & 1) * 64;
    const int fr = lane & 15, fq = lane >> 4;

    const int srow   = wid * 8 + (lane >> 3);
    const int scolsw = 8 * ((lane & 7) ^ (lane >> 3));
    const ushort* aSrc[4]; const ushort* bSrc[4];
    #pragma unroll
    for (int j = 0; j < 4; ++j) {
        int ra = m0 + j * 32 + srow; if (ra >= M) ra = M - 1;
        aSrc[j] = Ag + (size_t)ra * KK + scolsw;
        bSrc[j] = Wg + (size_t)(n0 + j * 32 + srow) * KK + scolsw;
    }

    f32x4 acc[4][4] = {};

    auto STAGE = [&](int buf, int k0) {
        #pragma unroll
        for (int j = 0; j < 4; ++j) {
            gload_lds16(aSrc[j] + k0, &As[buf][(j * 32 + wid * 8) * 64]);
            gload_lds16(bSrc[j] + k0, &Bs[buf][(j * 32 + wid * 8) * 64]);
        }
    };

    auto COMPUTE = [&](int buf) {
        #pragma unroll
        for (int ks = 0; ks < 2; ++ks) {
            bf16x8 af[4], bfr[4];
            #pragma unroll
            for (int i = 0; i < 4; ++i)
                af[i] = *(const bf16x8*)&As[buf][(wm + i * 16 + fr) * 64 +
                                                ((ks * 32 + fq * 8) ^ ((fr & 7) * 8))];
            #pragma unroll
            for (int j = 0; j < 4; ++j)
                bfr[j] = *(const bf16x8*)&Bs[buf][(wn + j * 16 + fr) * 64 +
                                                 ((ks * 32 + fq * 8) ^ ((fr & 7) * 8))];
            #pragma unroll
            for (int i = 0; i < 4; ++i)
                #pragma unroll
                for (int j = 0; j < 4; ++j)
                    acc[i][j] = MFMA16(af[i], bfr[j], acc[i][j]);
        }
    };

    constexpr int NT = KK / 64;
    STAGE(0, 0);
    STAGE(1, 64);
    #pragma unroll
    for (int t = 0; t < NT; ++t) {
        if (t + 1 < NT) asm volatile("s_waitcnt vmcnt(8)" ::: "memory");
        else asm volatile("s_waitcnt vmcnt(0)" ::: "memory");
        __builtin_amdgcn_s_barrier();
        __builtin_amdgcn_sched_barrier(0);
        COMPUTE(t & 1);
        __builtin_amdgcn_sched_barrier(0);
        __builtin_amdgcn_s_barrier();
        __builtin_amdgcn_sched_barrier(0);
        if (t + 2 < NT) STAGE(t & 1, (t + 2) * 64);
    }

    #pragma unroll
    for (int i = 0; i < 4; ++i) {
        #pragma unroll
        for (int e = 0; e < 4; ++e) {
            int row = m0 + wm + i * 16 + fq * 4 + e;
            if (row >= M) continue;
            #pragma unroll
            for (int j = 0; j < 4; ++j) {
                int col = n0 + wn + j * 16 + fr;
                float v = acc[i][j][e];
                if constexpr (EPI != EPI_STORE) v += bias[col];
                if constexpr (EPI == EPI_BIAS_GELU) v = 0.5f * v * (1.0f + erff(v * 0.70710678118654752f));
                if constexpr (EPI == EPI_STORE || EPI == EPI_BIAS_STORE || EPI == EPI_BIAS_GELU) {
                    Cg[(size_t)row * N + col] = f2bf(v);
                } else if constexpr (EPI == EPI_BIAS_ADD) {
                    xf[(size_t)row * DIM + col] += v;
                } else {  // EPI_BIAS_INIT_TFC: out = x + v, row remap
                    int t2 = row & 7, pp = (row >> 3) % HW_, bb = row / (HW_ * T_);
                    size_t dst = ((size_t)(bb * T_ + t2) * NTOK + 1 + pp) * DIM + col;
                    xf[dst] = xsrc[dst] + v;
                }
            }
        }
    }
}

// ---------------------------------------------------------------------------
// LayerNorm fp32 src -> bf16 dst (768 wide, 1 wave/row)
// ---------------------------------------------------------------------------
__global__ __launch_bounds__(256) void ln_f32(
    const float* __restrict__ src, const float* __restrict__ g,
    const float* __restrict__ b, ushort* __restrict__ dst, int rows)
{
    int widx = threadIdx.x >> 6, lane = threadIdx.x & 63;
    int r = blockIdx.x * 4 + widx;
    if (r >= rows) return;
    const float* row = src + (size_t)r * DIM;
    float v[12], sum = 0.f, sq = 0.f;
    #pragma unroll
    for (int c = 0; c < 3; ++c) {
        float4 t = *(const float4*)(row + c * 256 + lane * 4);
        v[c*4+0] = t.x; v[c*4+1] = t.y; v[c*4+2] = t.z; v[c*4+3] = t.w;
        sum += t.x + t.y + t.z + t.w;
        sq  += t.x*t.x + t.y*t.y + t.z*t.z + t.w*t.w;
    }
    sum = wred_sum(sum); sq = wred_sum(sq);
    float mean = sum * (1.f / DIM);
    float var  = sq * (1.f / DIM) - mean * mean;
    float rstd = rsqrtf(var + 1e-5f);
    #pragma unroll
    for (int c = 0; c < 3; ++c) {
        int idx = c * 256 + lane * 4;
        float4 gg = *(const float4*)(g + idx);
        float4 bb = *(const float4*)(b + idx);
        ushort4 o;
        o.x = f2bf((v[c*4+0] - mean) * rstd * gg.x + bb.x);
        o.y = f2bf((v[c*4+1] - mean) * rstd * gg.y + bb.y);
        o.z = f2bf((v[c*4+2] - mean) * rstd * gg.z + bb.z);
        o.w = f2bf((v[c*4+3] - mean) * rstd * gg.w + bb.w);
        *(ushort4*)(dst + (size_t)r * DIM + idx) = o;
    }
}

// Temporal gather + LN: out row r=(b*196+p)*8+t  <-  x[(b*8+t)][1+p][:]
__global__ __launch_bounds__(256) void ln_gather(
    const float* __restrict__ x, const float* __restrict__ g,
    const float* __restrict__ b, ushort* __restrict__ dst, int rows)
{
    int widx = threadIdx.x >> 6, lane = threadIdx.x & 63;
    int r = blockIdx.x * 4 + widx;
    if (r >= rows) return;
    int t = r & 7, pp = (r >> 3) % HW_, bb = r / (HW_ * T_);
    const float* row = x + ((size_t)(bb * T_ + t) * NTOK + 1 + pp) * DIM;
    float v[12], sum = 0.f, sq = 0.f;
    #pragma unroll
    for (int c = 0; c < 3; ++c) {
        float4 t4 = *(const float4*)(row + c * 256 + lane * 4);
        v[c*4+0] = t4.x; v[c*4+1] = t4.y; v[c*4+2] = t4.z; v[c*4+3] = t4.w;
        sum += t4.x + t4.y + t4.z + t4.w;
        sq  += t4.x*t4.x + t4.y*t4.y + t4.z*t4.z + t4.w*t4.w;
    }
    sum = wred_sum(sum); sq = wred_sum(sq);
    float mean = sum * (1.f / DIM);
    float var  = sq * (1.f / DIM) - mean * mean;
    float rstd = rsqrtf(var + 1e-5f);
    #pragma unroll
    for (int c = 0; c < 3; ++c) {
        int idx = c * 256 + lane * 4;
        float4 gg = *(const float4*)(g + idx);
        float4 bb2 = *(const float4*)(b + idx);
        ushort4 o;
        o.x = f2bf((v[c*4+0] - mean) * rstd * gg.x + bb2.x);
        o.y = f2bf((v[c*4+1] - mean) * rstd * gg.y + bb2.y);
        o.z = f2bf((v[c*4+2] - mean) * rstd * gg.z + bb2.z);
        o.w = f2bf((v[c*4+3] - mean) * rstd * gg.w + bb2.w);
        *(ushort4*)(dst + (size_t)r * DIM + idx) = o;
    }
}

// ---------------------------------------------------------------------------
// Temporal attention: seq len 8, one wave per (seq, head); lane=(qi*8+kj)
// ---------------------------------------------------------------------------
__global__ __launch_bounds__(256) void attn_temporal(
    const ushort* __restrict__ qkv, ushort* __restrict__ O)
{
    int widx = threadIdx.x >> 6, lane = threadIdx.x & 63;
    int w = blockIdx.x * 4 + widx;
    int s = w / NH, h = w % NH;
    int qi = lane >> 3, kj = lane & 7;

    const ushort* qrow = qkv + (size_t)(s * 8 + qi) * (3 * DIM) + h * HD;
    const ushort* krow = qkv + (size_t)(s * 8 + kj) * (3 * DIM) + DIM + h * HD;
    float d = 0.f;
    #pragma unroll
    for (int c = 0; c < 8; ++c) {
        uint4 qa = *(const uint4*)(qrow + c * 8);
        uint4 ka = *(const uint4*)(krow + c * 8);
        const ushort* qs = (const ushort*)&qa;
        const ushort* ks = (const ushort*)&ka;
        #pragma unroll
        for (int e = 0; e < 8; ++e) d += bf2f(qs[e]) * bf2f(ks[e]);
    }
    float sc = d * 0.125f;
    float mx = sc;
    #pragma unroll
    for (int m = 4; m; m >>= 1) mx = fmaxf(mx, __shfl_xor(mx, m));
    float p = expf(sc - mx);
    float sum = p;
    #pragma unroll
    for (int m = 4; m; m >>= 1) sum += __shfl_xor(sum, m);
    p /= sum;

    float o[8] = {};
    int base = lane & ~7;
    #pragma unroll
    for (int t = 0; t < 8; ++t) {
        float pt = __shfl(p, base + t);
        const ushort* vrow = qkv + (size_t)(s * 8 + t) * (3 * DIM) + 2 * DIM + h * HD + kj * 8;
        uint4 va = *(const uint4*)vrow;
        const ushort* vs = (const ushort*)&va;
        #pragma unroll
        for (int e = 0; e < 8; ++e) o[e] += pt * bf2f(vs[e]);
    }
    ushort out[8];
    #pragma unroll
    for (int e = 0; e < 8; ++e) out[e] = f2bf(o[e]);
    *(uint4*)(O + (size_t)(s * 8 + qi) * DIM + h * HD + kj * 8) = *(const uint4*)out;
}

// ---------------------------------------------------------------------------
// Spatial attention, MFMA. One block per (s,h); 4 waves; 768 blocks.
// ---------------------------------------------------------------------------
#define KS_STRIDE 72
#define VT_STRIDE 208
#define P_STRIDE  208
#define KS_OFF    0
#define VT_OFF    (197 * KS_STRIDE)
#define P_OFF     (VT_OFF + 64 * VT_STRIDE)
#define LDS_TOT   (P_OFF + 4 * 16 * P_STRIDE)

__global__ __launch_bounds__(256, 2) void attn_spatial_mfma(
    const ushort* __restrict__ qkv, ushort* __restrict__ O)
{
    __shared__ ushort lds[LDS_TOT];
    const int tid = threadIdx.x, lane = tid & 63, wid = tid >> 6;
    const int fr = lane & 15, fq = lane >> 4;
    int lin = xcd_lin(blockIdx.x, BT_ * NH);
    const int s = lin / NH, h = lin % NH;
    const size_t base = (size_t)s * NTOK * (3 * DIM);
    const ushort* Qg = qkv + base + h * HD;
    const ushort* Kg = qkv + base + DIM + h * HD;
    const ushort* Vg = qkv + base + 2 * DIM + h * HD;

    for (int chunk = tid; chunk < NTOK * 8; chunk += 256) {
        int r = chunk >> 3, c = (chunk & 7) * 8;
        uint4 v = *(const uint4*)(Kg + (size_t)r * (3 * DIM) + c);
        *(uint4*)&lds[KS_OFF + r * KS_STRIDE + c] = v;
    }
    for (int chunk = tid; chunk < 208 * 8; chunk += 256) {
        int k = chunk >> 3, c = (chunk & 7) * 8;
        uint4 v = {0u, 0u, 0u, 0u};
        if (k < NTOK) v = *(const uint4*)(Vg + (size_t)k * (3 * DIM) + c);
        const ushort* e = (const ushort*)&v;
        #pragma unroll
        for (int j = 0; j < 8; ++j) lds[VT_OFF + (c + j) * VT_STRIDE + k] = e[j];
    }
    __syncthreads();

    ushort* P = &lds[P_OFF + wid * 16 * P_STRIDE];

    for (int qi = wid; qi < 13; qi += 4) {
        int qrow = qi * 16 + fr; if (qrow > NTOK - 1) qrow = NTOK - 1;
        bf16x8 qf0 = *(const bf16x8*)(Qg + (size_t)qrow * (3 * DIM) + fq * 8);
        bf16x8 qf1 = *(const bf16x8*)(Qg + (size_t)qrow * (3 * DIM) + 32 + fq * 8);

        f32x4 sacc[13];
        #pragma unroll
        for (int t = 0; t < 13; ++t) {
            bf16x8 kf0 = *(const bf16x8*)&lds[KS_OFF + (t * 16 + fr) * KS_STRIDE + fq * 8];
            bf16x8 kf1 = *(const bf16x8*)&lds[KS_OFF + (t * 16 + fr) * KS_STRIDE + 32 + fq * 8];
            f32x4 z = {0.f, 0.f, 0.f, 0.f};
            z = MFMA16(kf0, qf0, z);
            sacc[t] = MFMA16(kf1, qf1, z);
        }

        float m = -1e30f;
        #pragma unroll
        for (int t = 0; t < 13; ++t)
            #pragma unroll
            for (int e = 0; e < 4; ++e) {
                int k = t * 16 + fq * 4 + e;
                float v = (k < NTOK) ? sacc[t][e] * 0.125f : -1e30f;
                sacc[t][e] = v;
                m = fmaxf(m, v);
            }
        m = fmaxf(m, __shfl_xor(m, 16));
        m = fmaxf(m, __shfl_xor(m, 32));
        float sum = 0.f;
        #pragma unroll
        for (int t = 0; t < 13; ++t)
            #pragma unroll
            for (int e = 0; e < 4; ++e) {
                float p = expf(sacc[t][e] - m);
                sacc[t][e] = p;
                sum += p;
            }
        sum += __shfl_xor(sum, 16);
        sum += __shfl_xor(sum, 32);
        float rd = 1.f / sum;

        #pragma unroll
        for (int t = 0; t < 13; ++t) {
            ushort2 w0 = { f2bf(sacc[t][0] * rd), f2bf(sacc[t][1] * rd) };
            ushort2 w1 = { f2bf(sacc[t][2] * rd), f2bf(sacc[t][3] * rd) };
            *(ushort2*)&P[fr * P_STRIDE + t * 16 + fq * 4]     = w0;
            *(ushort2*)&P[fr * P_STRIDE + t * 16 + fq * 4 + 2] = w1;
        }

        f32x4 oacc[4] = {};
        #pragma unroll
        for (int st = 0; st < 6; ++st) {
            bf16x8 pf = *(const bf16x8*)&P[fr * P_STRIDE + st * 32 + fq * 8];
            #pragma unroll
            for (int dt = 0; dt < 4; ++dt) {
                bf16x8 vf = *(const bf16x8*)&lds[VT_OFF + (dt * 16 + fr) * VT_STRIDE + st * 32 + fq * 8];
                oacc[dt] = MFMA16(pf, vf, oacc[dt]);
            }
        }
        {
            bf16x8 zz = {};
            bf16x8 pf = zz;
            if (fq < 2) pf = *(const bf16x8*)&P[fr * P_STRIDE + 192 + fq * 8];
            #pragma unroll
            for (int dt = 0; dt < 4; ++dt) {
                bf16x8 vf = zz;
                if (fq < 2) vf = *(const bf16x8*)&lds[VT_OFF + (dt * 16 + fr) * VT_STRIDE + 192 + fq * 8];
                oacc[dt] = MFMA16(pf, vf, oacc[dt]);
            }
        }

        #pragma unroll
        for (int dt = 0; dt < 4; ++dt)
            #pragma unroll
            for (int e = 0; e < 4; ++e) {
                int q = qi * 16 + fq * 4 + e;
                if (q < NTOK)
                    O[(size_t)(s * NTOK + q) * DIM + h * HD + dt * 16 + fr] = f2bf(oacc[dt][e]);
            }
    }
}

// ---------------------------------------------------------------------------
extern "C" void kernel_launch(void* const* d_in, const int* in_sizes, int n_in,
                              void* d_out, int out_size, void* d_ws, size_t ws_size,
                              hipStream_t stream)
{
    const float* x      = (const float*)d_in[0];
    const float* ln1_g  = (const float*)d_in[1];
    const float* ln1_b  = (const float*)d_in[2];
    const float* qkv_w  = (const float*)d_in[3];
    const float* proj_w = (const float*)d_in[4];
    const float* proj_b = (const float*)d_in[5];
    const float* tln_g  = (const float*)d_in[6];
    const float* tln_b  = (const float*)d_in[7];
    const float* tqkv_w = (const float*)d_in[8];
    const float* tproj_w= (const float*)d_in[9];
    const float* tproj_b= (const float*)d_in[10];
    const float* tfc_w  = (const float*)d_in[11];
    const float* tfc_b  = (const float*)d_in[12];
    const float* ln2_g  = (const float*)d_in[13];
    const float* ln2_b  = (const float*)d_in[14];
    const float* fc1_w  = (const float*)d_in[15];
    const float* fc1_b  = (const float*)d_in[16];
    const float* fc2_w  = (const float*)d_in[17];
    const float* fc2_b  = (const float*)d_in[18];

    float* out = (float*)d_out;   // fp32 residual accumulator = final output

    char* p = (char*)d_ws;
    ushort* w_qkv  = (ushort*)p; p += (size_t)(3*DIM*DIM) * 2;
    ushort* w_proj = (ushort*)p; p += (size_t)(DIM*DIM) * 2;
    ushort* w_tqkv = (ushort*)p; p += (size_t)(3*DIM*DIM) * 2;
    ushort* w_tproj= (ushort*)p; p += (size_t)(DIM*DIM) * 2;
    ushort* w_tfc  = (ushort*)p; p += (size_t)(DIM*DIM) * 2;
    ushort* w_fc1  = (ushort*)p; p += (size_t)(HID*DIM) * 2;
    ushort* w_fc2  = (ushort*)p; p += (size_t)(HID*DIM) * 2;
    ushort* bufA   = (ushort*)p; p += (size_t)MROWS * DIM * 2;
    ushort* bufC   = (ushort*)p; p += (size_t)MROWS * DIM * 2;
    ushort* bufB   = (ushort*)p;  // MROWS*3*DIM bf16

    {
        const int DD8 = DIM * DIM / 8;
        int c0 = 3 * DD8;
        int c1 = c0 + DD8;
        int c2 = c1 + 3 * DD8;
        int c3 = c2 + DD8;
        int c4 = c3 + DD8;
        int c5 = c4 + HID * DIM / 8;
        int c6 = c5 + HID * DIM / 8;
        cast_all<<<dim3((c6 + 255) / 256), dim3(256), 0, stream>>>(
            qkv_w, w_qkv, c0, proj_w, w_proj, c1, tqkv_w, w_tqkv, c2,
            tproj_w, w_tproj, c3, tfc_w, w_tfc, c4, fc1_w, w_fc1, c5,
            fc2_w, w_fc2, c6);
    }

    init_cls<<<dim3(48), dim3(256), 0, stream>>>(x, out);

    #define GEMM(EPI, KV, A, W, BIAS, C, XS, XF, M, N, GRP) \
        gemm_bt<EPI, KV><<<dim3((((M) + 127) / 128) * ((N) / 128)), dim3(256), 0, stream>>>( \
            A, W, BIAS, C, XS, XF, M, N, ((M) + 127) / 128, (N) / 128, GRP)
    #define GEMM256(KV, A, W, C, M, N, GRP) \
        gemm256<KV><<<dim3((((M) + 255) / 256) * ((N) / 256)), dim3(512), 0, stream>>>( \
            A, W, C, M, N, ((M) + 255) / 256, (N) / 256, GRP)

    // ---- temporal branch ----
    ln_gather<<<dim3(TROWS / 4), dim3(256), 0, stream>>>(x, tln_g, tln_b, bufA, TROWS);
    GEMM256(DIM, bufA, w_tqkv, bufB, TROWS, 3 * DIM, 1);
    attn_temporal<<<dim3(TROWS * NH / 8 / 4), dim3(256), 0, stream>>>(bufB, bufC);
    GEMM(EPI_BIAS_STORE, DIM, bufC, w_tproj, tproj_b, bufA, nullptr, nullptr, TROWS, DIM, 8);
    GEMM(EPI_BIAS_INIT_TFC, DIM, bufA, w_tfc, tfc_b, nullptr, x, out, TROWS, DIM, 8);

    // ---- spatial attention ----
    ln_f32<<<dim3((MROWS + 3) / 4), dim3(256), 0, stream>>>(out, ln1_g, ln1_b, bufA, MROWS);
    GEMM256(DIM, bufA, w_qkv, bufB, MROWS, 3 * DIM, 1);
    attn_spatial_mfma<<<dim3(BT_ * NH), dim3(256), 0, stream>>>(bufB, bufC);
    GEMM(EPI_BIAS_ADD, DIM, bufC, w_proj, proj_b, nullptr, nullptr, out, MROWS, DIM, 8);

    // ---- MLP ----
    ln_f32<<<dim3((MROWS + 3) / 4), dim3(256), 0, stream>>>(out, ln2_g, ln2_b, bufA, MROWS);
    GEMM(EPI_BIAS_GELU, DIM, bufA, w_fc1, fc1_b, bufB, nullptr, nullptr, MROWS, HID, 8);
    GEMM(EPI_BIAS_ADD, HID, bufB, w_fc2, fc2_b, nullptr, nullptr, out, MROWS, DIM, 4);
    #undef GEMM
    #undef GEMM256
}

// Round 7
// 412.328 us; speedup vs baseline: 5.9255x; 1.0077x over previous
//
#include <hip/hip_runtime.h>
#include <hip/hip_bf16.h>

// ---------------------------------------------------------------------------
// FactorizedAttentionBlock (TimeSformer divided space-time attention)
// DIM=768, NH=12, HD=64, HID=1152(pad 1280), B=8, T=8, HW=196, N=197, BT=64
// FP32 in/out. bf16 MFMA GEMMs + MFMA flash attention. fp32 residual in d_out.
// R7: tproj∘tfc composed into one GEMM (W_comb = tfc@tproj on device);
//     ALL GEMMs use the 256x256 8-wave 4-phase kernel; fc1/fc2 padded to
//     HID'=1280 so N is a multiple of 256. gemm_bt deleted.
// ---------------------------------------------------------------------------

#define DIM   768
#define NH    12
#define HD    64
#define HID   1152
#define HIDP  1280
#define B_    8
#define T_    8
#define HW_   196
#define NTOK  197
#define BT_   64
#define MROWS (BT_ * NTOK)        // 12608
#define TROWS (B_ * HW_ * T_)     // 12544

typedef __bf16 bf16x8 __attribute__((ext_vector_type(8)));
typedef float  f32x4  __attribute__((ext_vector_type(4)));

__device__ inline float bf2f(ushort u) { return __uint_as_float(((unsigned)u) << 16); }
__device__ inline ushort f2bf(float f) {
    unsigned u = __float_as_uint(f);
    unsigned r = (u + 0x7fffu + ((u >> 16) & 1u)) >> 16;
    return (ushort)r;
}

__device__ inline float wred_sum(float v) {
    #pragma unroll
    for (int m = 32; m; m >>= 1) v += __shfl_xor(v, m);
    return v;
}

__device__ __forceinline__ void gload_lds16(const void* g, void* l) {
    __builtin_amdgcn_global_load_lds(
        (const __attribute__((address_space(1))) unsigned int*)g,
        (__attribute__((address_space(3))) unsigned int*)l, 16, 0, 0);
}

// XCD-bijective remap (m204)
__device__ __forceinline__ int xcd_lin(int gid, int nwg) {
    int q = nwg >> 3, r = nwg & 7;
    int xcd = gid & 7, idx = gid >> 3;
    return (xcd < r ? xcd * (q + 1) : r * (q + 1) + (xcd - r) * q) + idx;
}

#define MFMA16(a, b, c) __builtin_amdgcn_mfma_f32_16x16x32_bf16(a, b, c, 0, 0, 0)

// ---------------------------------------------------------------------------
// small prep kernels
// ---------------------------------------------------------------------------
__global__ __launch_bounds__(256) void cast_all(
    const float* s0, ushort* d0, int c0, const float* s1, ushort* d1, int c1,
    const float* s2, ushort* d2, int c2, const float* s3, ushort* d3, int c3,
    const float* s4, ushort* d4, int c4)
{
    int i = blockIdx.x * 256 + threadIdx.x;
    const float* s; ushort* d; int base;
    if      (i < c0) { s = s0; d = d0; base = 0;  }
    else if (i < c1) { s = s1; d = d1; base = c0; }
    else if (i < c2) { s = s2; d = d2; base = c1; }
    else if (i < c3) { s = s3; d = d3; base = c2; }
    else if (i < c4) { s = s4; d = d4; base = c3; }
    else return;
    int k = i - base;
    float4 a = *(const float4*)(s + (size_t)k * 8);
    float4 b = *(const float4*)(s + (size_t)k * 8 + 4);
    ushort o[8] = {f2bf(a.x), f2bf(a.y), f2bf(a.z), f2bf(a.w),
                   f2bf(b.x), f2bf(b.y), f2bf(b.z), f2bf(b.w)};
    *(uint4*)(d + (size_t)k * 8) = *(const uint4*)o;
}

// tprojT[n][k] = tproj[k][n], fp32 -> bf16 (tiled transpose)
__global__ __launch_bounds__(256) void transpose_cast(const float* __restrict__ in, ushort* __restrict__ out)
{
    __shared__ float t[32][33];
    int bx = blockIdx.x % 24, by = blockIdx.x / 24;
    int lx = threadIdx.x & 31, ly = threadIdx.x >> 5;   // 32 x 8
    #pragma unroll
    for (int i = 0; i < 32; i += 8)
        t[ly + i][lx] = in[(size_t)(by * 32 + ly + i) * DIM + bx * 32 + lx];
    __syncthreads();
    #pragma unroll
    for (int i = 0; i < 32; i += 8)
        out[(size_t)(bx * 32 + ly + i) * DIM + by * 32 + lx] = f2bf(t[lx][ly + i]);
}

// fc2 weight: [768][1152] fp32 -> [768][1280] bf16, pad cols zero
__global__ __launch_bounds__(256) void cast_pad_fc2(const float* __restrict__ in, ushort* __restrict__ out)
{
    int i = blockIdx.x * 256 + threadIdx.x;
    if (i >= DIM * (HIDP / 8)) return;
    int r = i / (HIDP / 8), c8 = (i % (HIDP / 8)) * 8;
    ushort o[8];
    if (c8 < HID) {
        const float* s = in + (size_t)r * HID + c8;
        #pragma unroll
        for (int e = 0; e < 8; ++e) o[e] = f2bf(s[e]);
    } else {
        #pragma unroll
        for (int e = 0; e < 8; ++e) o[e] = 0;
    }
    *(uint4*)(out + (size_t)r * HIDP + c8) = *(const uint4*)o;
}

// fc1 bias padded to 1280
__global__ __launch_bounds__(256) void pad_bias(const float* __restrict__ in, float* __restrict__ out)
{
    int i = blockIdx.x * 256 + threadIdx.x;
    if (i < HIDP) out[i] = (i < HID) ? in[i] : 0.f;
}

// b_comb[i] = dot(tfc_w[i,:], tproj_b) + tfc_b[i]
__global__ __launch_bounds__(256) void bias_comb(
    const float* __restrict__ tfc_w, const float* __restrict__ tproj_b,
    const float* __restrict__ tfc_b, float* __restrict__ bc)
{
    int w = blockIdx.x * 4 + (threadIdx.x >> 6);
    int lane = threadIdx.x & 63;
    float s = 0.f;
    for (int j = lane; j < DIM; j += 64) s += tfc_w[(size_t)w * DIM + j] * tproj_b[j];
    s = wred_sum(s);
    if (lane == 0) bc[w] = s + tfc_b[w];
}

// init cls rows of out: out[s*197 + 0][:] = x[s*197 + 0][:]
__global__ __launch_bounds__(256) void init_cls(const float* __restrict__ x, float* __restrict__ out)
{
    int i = blockIdx.x * 256 + threadIdx.x;     // 64 * 192 float4
    int r = i / 192, c = (i % 192) * 4;
    size_t off = ((size_t)r * NTOK) * DIM + c;
    *(float4*)(out + off) = *(const float4*)(x + off);
}

// ---------------------------------------------------------------------------
// gemm256: C[M,N] = A[M,K] @ W[N,K]^T (+bias)(+epi). 256x256 tile, 8 waves
// (2Mx4N), per-wave 128x64. BK=64, dbuf LDS (128KB), 4 phases/K-tile,
// one vmcnt(0)+s_barrier per K-tile, setprio on MFMA clusters, XOR swizzle.
// ---------------------------------------------------------------------------
enum { EPI_STORE = 0, EPI_BIAS_GELU = 1, EPI_BIAS_ADD = 2, EPI_INIT_TFC = 3 };

template <int KK, int EPI>
__global__ __launch_bounds__(512, 1) void gemm256(
    const ushort* __restrict__ Ag, const ushort* __restrict__ Wg,
    const float* __restrict__ bias, ushort* __restrict__ Cg,
    const float* __restrict__ xsrc, float* __restrict__ xf,
    int M, int N, int nm, int nn, int grp)
{
    __shared__ ushort As[2][256 * 64];
    __shared__ ushort Bs[2][256 * 64];

    const int tid  = threadIdx.x;
    const int lane = tid & 63, wid = tid >> 6;
    const int wr = wid >> 2, wc = wid & 3;
    const int fr = lane & 15, fq = lane >> 4;

    int lin = xcd_lin(blockIdx.x, nm * nn);
    int per = grp * nn;
    int g2 = lin / per, rem = lin % per;
    int bm = g2 * grp;
    int gm = nm - bm; if (gm > grp) gm = grp;
    const int m0 = (bm + rem % gm) * 256;
    const int n0 = (rem / gm) * 256;

    const int srow = wid * 8 + (lane >> 3);
    const int scol = 8 * ((lane & 7) ^ (lane >> 3));
    const ushort* aP[4]; const ushort* bP[4];
    #pragma unroll
    for (int j = 0; j < 4; ++j) {
        int ra = m0 + j * 64 + srow; if (ra >= M) ra = M - 1;
        aP[j] = Ag + (size_t)ra * KK + scol;
        bP[j] = Wg + (size_t)(n0 + j * 64 + srow) * KK + scol;
    }
    const int ldso = (wid * 8) * 64;

    f32x4 acc[8][4] = {};
    bf16x8 af[4][2], b0[2][2], b1[2][2];

    const int sw0 = (fq * 8) ^ ((fr & 7) * 8);
    const int sw1 = (32 + fq * 8) ^ ((fr & 7) * 8);

    #pragma unroll
    for (int j = 0; j < 4; ++j) gload_lds16(aP[j], &As[0][j * 4096 + ldso]);
    #pragma unroll
    for (int j = 0; j < 4; ++j) gload_lds16(bP[j], &Bs[0][j * 4096 + ldso]);

    constexpr int NT = KK / 64;
    #pragma unroll
    for (int t = 0; t < NT; ++t) {
        const int rb = t & 1, wb = rb ^ 1;
        const bool st = (t + 1 < NT);
        const int kw = (t + 1) * 64;

        asm volatile("s_waitcnt vmcnt(0)" ::: "memory");
        __builtin_amdgcn_s_barrier();
        __builtin_amdgcn_sched_barrier(0);

        // ---- phase 0 ----
        #pragma unroll
        for (int mf = 0; mf < 4; ++mf) {
            af[mf][0] = *(const bf16x8*)&As[rb][(wr * 128 + mf * 16 + fr) * 64 + sw0];
            af[mf][1] = *(const bf16x8*)&As[rb][(wr * 128 + mf * 16 + fr) * 64 + sw1];
        }
        #pragma unroll
        for (int nf = 0; nf < 2; ++nf) {
            b0[nf][0] = *(const bf16x8*)&Bs[rb][(wc * 64 + nf * 16 + fr) * 64 + sw0];
            b0[nf][1] = *(const bf16x8*)&Bs[rb][(wc * 64 + nf * 16 + fr) * 64 + sw1];
        }
        if (st) {
            #pragma unroll
            for (int j = 0; j < 4; ++j) gload_lds16(aP[j] + kw, &As[wb][j * 4096 + ldso]);
        }
        asm volatile("s_waitcnt lgkmcnt(0)" ::: "memory");
        __builtin_amdgcn_sched_barrier(0);
        __builtin_amdgcn_s_setprio(1);
        #pragma unroll
        for (int mf = 0; mf < 4; ++mf)
            #pragma unroll
            for (int nf = 0; nf < 2; ++nf) {
                acc[mf][nf] = MFMA16(af[mf][0], b0[nf][0], acc[mf][nf]);
                acc[mf][nf] = MFMA16(af[mf][1], b0[nf][1], acc[mf][nf]);
            }
        __builtin_amdgcn_s_setprio(0);
        __builtin_amdgcn_sched_barrier(0);

        // ---- phase 1 ----
        #pragma unroll
        for (int nf = 0; nf < 2; ++nf) {
            b1[nf][0] = *(const bf16x8*)&Bs[rb][(wc * 64 + (nf + 2) * 16 + fr) * 64 + sw0];
            b1[nf][1] = *(const bf16x8*)&Bs[rb][(wc * 64 + (nf + 2) * 16 + fr) * 64 + sw1];
        }
        if (st) {
            #pragma unroll
            for (int j = 0; j < 4; ++j) gload_lds16(bP[j] + kw, &Bs[wb][j * 4096 + ldso]);
        }
        asm volatile("s_waitcnt lgkmcnt(0)" ::: "memory");
        __builtin_amdgcn_sched_barrier(0);
        __builtin_amdgcn_s_setprio(1);
        #pragma unroll
        for (int mf = 0; mf < 4; ++mf)
            #pragma unroll
            for (int nf = 0; nf < 2; ++nf) {
                acc[mf][nf + 2] = MFMA16(af[mf][0], b1[nf][0], acc[mf][nf + 2]);
                acc[mf][nf + 2] = MFMA16(af[mf][1], b1[nf][1], acc[mf][nf + 2]);
            }
        __builtin_amdgcn_s_setprio(0);
        __builtin_amdgcn_sched_barrier(0);

        // ---- phase 2 ----
        #pragma unroll
        for (int mf = 0; mf < 4; ++mf) {
            af[mf][0] = *(const bf16x8*)&As[rb][(wr * 128 + 64 + mf * 16 + fr) * 64 + sw0];
            af[mf][1] = *(const bf16x8*)&As[rb][(wr * 128 + 64 + mf * 16 + fr) * 64 + sw1];
        }
        asm volatile("s_waitcnt lgkmcnt(0)" ::: "memory");
        __builtin_amdgcn_sched_barrier(0);
        __builtin_amdgcn_s_setprio(1);
        #pragma unroll
        for (int mf = 0; mf < 4; ++mf)
            #pragma unroll
            for (int nf = 0; nf < 2; ++nf) {
                acc[mf + 4][nf] = MFMA16(af[mf][0], b0[nf][0], acc[mf + 4][nf]);
                acc[mf + 4][nf] = MFMA16(af[mf][1], b0[nf][1], acc[mf + 4][nf]);
            }
        __builtin_amdgcn_s_setprio(0);
        __builtin_amdgcn_sched_barrier(0);

        // ---- phase 3 ----
        __builtin_amdgcn_s_setprio(1);
        #pragma unroll
        for (int mf = 0; mf < 4; ++mf)
            #pragma unroll
            for (int nf = 0; nf < 2; ++nf) {
                acc[mf + 4][nf + 2] = MFMA16(af[mf][0], b1[nf][0], acc[mf + 4][nf + 2]);
                acc[mf + 4][nf + 2] = MFMA16(af[mf][1], b1[nf][1], acc[mf + 4][nf + 2]);
            }
        __builtin_amdgcn_s_setprio(0);
        __builtin_amdgcn_sched_barrier(0);
    }

    // epilogue: row = m0 + wr*128 + mf*16 + fq*4 + e; col = n0 + wc*64 + nf*16 + fr
    #pragma unroll
    for (int mf = 0; mf < 8; ++mf)
        #pragma unroll
        for (int e = 0; e < 4; ++e) {
            int row = m0 + wr * 128 + mf * 16 + fq * 4 + e;
            if (row >= M) continue;
            size_t dstrow = 0;
            if constexpr (EPI == EPI_INIT_TFC) {
                int t2 = row & 7, pp = (row >> 3) % HW_, bb = row / (HW_ * T_);
                dstrow = ((size_t)(bb * T_ + t2) * NTOK + 1 + pp) * DIM;
            }
            #pragma unroll
            for (int nf = 0; nf < 4; ++nf) {
                int col = n0 + wc * 64 + nf * 16 + fr;
                float v = acc[mf][nf][e];
                if constexpr (EPI != EPI_STORE) v += bias[col];
                if constexpr (EPI == EPI_BIAS_GELU) v = 0.5f * v * (1.0f + erff(v * 0.70710678118654752f));
                if constexpr (EPI == EPI_STORE || EPI == EPI_BIAS_GELU) {
                    Cg[(size_t)row * N + col] = f2bf(v);
                } else if constexpr (EPI == EPI_BIAS_ADD) {
                    xf[(size_t)row * DIM + col] += v;
                } else {
                    xf[dstrow + col] = xsrc[dstrow + col] + v;
                }
            }
        }
}

// ---------------------------------------------------------------------------
// LayerNorm fp32 src -> bf16 dst (768 wide, 1 wave/row)
// ---------------------------------------------------------------------------
__global__ __launch_bounds__(256) void ln_f32(
    const float* __restrict__ src, const float* __restrict__ g,
    const float* __restrict__ b, ushort* __restrict__ dst, int rows)
{
    int widx = threadIdx.x >> 6, lane = threadIdx.x & 63;
    int r = blockIdx.x * 4 + widx;
    if (r >= rows) return;
    const float* row = src + (size_t)r * DIM;
    float v[12], sum = 0.f, sq = 0.f;
    #pragma unroll
    for (int c = 0; c < 3; ++c) {
        float4 t = *(const float4*)(row + c * 256 + lane * 4);
        v[c*4+0] = t.x; v[c*4+1] = t.y; v[c*4+2] = t.z; v[c*4+3] = t.w;
        sum += t.x + t.y + t.z + t.w;
        sq  += t.x*t.x + t.y*t.y + t.z*t.z + t.w*t.w;
    }
    sum = wred_sum(sum); sq = wred_sum(sq);
    float mean = sum * (1.f / DIM);
    float var  = sq * (1.f / DIM) - mean * mean;
    float rstd = rsqrtf(var + 1e-5f);
    #pragma unroll
    for (int c = 0; c < 3; ++c) {
        int idx = c * 256 + lane * 4;
        float4 gg = *(const float4*)(g + idx);
        float4 bb = *(const float4*)(b + idx);
        ushort4 o;
        o.x = f2bf((v[c*4+0] - mean) * rstd * gg.x + bb.x);
        o.y = f2bf((v[c*4+1] - mean) * rstd * gg.y + bb.y);
        o.z = f2bf((v[c*4+2] - mean) * rstd * gg.z + bb.z);
        o.w = f2bf((v[c*4+3] - mean) * rstd * gg.w + bb.w);
        *(ushort4*)(dst + (size_t)r * DIM + idx) = o;
    }
}

// Temporal gather + LN
__global__ __launch_bounds__(256) void ln_gather(
    const float* __restrict__ x, const float* __restrict__ g,
    const float* __restrict__ b, ushort* __restrict__ dst, int rows)
{
    int widx = threadIdx.x >> 6, lane = threadIdx.x & 63;
    int r = blockIdx.x * 4 + widx;
    if (r >= rows) return;
    int t = r & 7, pp = (r >> 3) % HW_, bb = r / (HW_ * T_);
    const float* row = x + ((size_t)(bb * T_ + t) * NTOK + 1 + pp) * DIM;
    float v[12], sum = 0.f, sq = 0.f;
    #pragma unroll
    for (int c = 0; c < 3; ++c) {
        float4 t4 = *(const float4*)(row + c * 256 + lane * 4);
        v[c*4+0] = t4.x; v[c*4+1] = t4.y; v[c*4+2] = t4.z; v[c*4+3] = t4.w;
        sum += t4.x + t4.y + t4.z + t4.w;
        sq  += t4.x*t4.x + t4.y*t4.y + t4.z*t4.z + t4.w*t4.w;
    }
    sum = wred_sum(sum); sq = wred_sum(sq);
    float mean = sum * (1.f / DIM);
    float var  = sq * (1.f / DIM) - mean * mean;
    float rstd = rsqrtf(var + 1e-5f);
    #pragma unroll
    for (int c = 0; c < 3; ++c) {
        int idx = c * 256 + lane * 4;
        float4 gg = *(const float4*)(g + idx);
        float4 bb2 = *(const float4*)(b + idx);
        ushort4 o;
        o.x = f2bf((v[c*4+0] - mean) * rstd * gg.x + bb2.x);
        o.y = f2bf((v[c*4+1] - mean) * rstd * gg.y + bb2.y);
        o.z = f2bf((v[c*4+2] - mean) * rstd * gg.z + bb2.z);
        o.w = f2bf((v[c*4+3] - mean) * rstd * gg.w + bb2.w);
        *(ushort4*)(dst + (size_t)r * DIM + idx) = o;
    }
}

// ---------------------------------------------------------------------------
// Temporal attention: seq len 8, one wave per (seq, head)
// ---------------------------------------------------------------------------
__global__ __launch_bounds__(256) void attn_temporal(
    const ushort* __restrict__ qkv, ushort* __restrict__ O)
{
    int widx = threadIdx.x >> 6, lane = threadIdx.x & 63;
    int w = blockIdx.x * 4 + widx;
    int s = w / NH, h = w % NH;
    int qi = lane >> 3, kj = lane & 7;

    const ushort* qrow = qkv + (size_t)(s * 8 + qi) * (3 * DIM) + h * HD;
    const ushort* krow = qkv + (size_t)(s * 8 + kj) * (3 * DIM) + DIM + h * HD;
    float d = 0.f;
    #pragma unroll
    for (int c = 0; c < 8; ++c) {
        uint4 qa = *(const uint4*)(qrow + c * 8);
        uint4 ka = *(const uint4*)(krow + c * 8);
        const ushort* qs = (const ushort*)&qa;
        const ushort* ks = (const ushort*)&ka;
        #pragma unroll
        for (int e = 0; e < 8; ++e) d += bf2f(qs[e]) * bf2f(ks[e]);
    }
    float sc = d * 0.125f;
    float mx = sc;
    #pragma unroll
    for (int m = 4; m; m >>= 1) mx = fmaxf(mx, __shfl_xor(mx, m));
    float p = expf(sc - mx);
    float sum = p;
    #pragma unroll
    for (int m = 4; m; m >>= 1) sum += __shfl_xor(sum, m);
    p /= sum;

    float o[8] = {};
    int base = lane & ~7;
    #pragma unroll
    for (int t = 0; t < 8; ++t) {
        float pt = __shfl(p, base + t);
        const ushort* vrow = qkv + (size_t)(s * 8 + t) * (3 * DIM) + 2 * DIM + h * HD + kj * 8;
        uint4 va = *(const uint4*)vrow;
        const ushort* vs = (const ushort*)&va;
        #pragma unroll
        for (int e = 0; e < 8; ++e) o[e] += pt * bf2f(vs[e]);
    }
    ushort out[8];
    #pragma unroll
    for (int e = 0; e < 8; ++e) out[e] = f2bf(o[e]);
    *(uint4*)(O + (size_t)(s * 8 + qi) * DIM + h * HD + kj * 8) = *(const uint4*)out;
}

// ---------------------------------------------------------------------------
// Spatial attention, MFMA. One block per (s,h); 4 waves; 768 blocks.
// ---------------------------------------------------------------------------
#define KS_STRIDE 72
#define VT_STRIDE 208
#define P_STRIDE  208
#define KS_OFF    0
#define VT_OFF    (197 * KS_STRIDE)
#define P_OFF     (VT_OFF + 64 * VT_STRIDE)
#define LDS_TOT   (P_OFF + 4 * 16 * P_STRIDE)

__global__ __launch_bounds__(256, 2) void attn_spatial_mfma(
    const ushort* __restrict__ qkv, ushort* __restrict__ O)
{
    __shared__ ushort lds[LDS_TOT];
    const int tid = threadIdx.x, lane = tid & 63, wid = tid >> 6;
    const int fr = lane & 15, fq = lane >> 4;
    int lin = xcd_lin(blockIdx.x, BT_ * NH);
    const int s = lin / NH, h = lin % NH;
    const size_t base = (size_t)s * NTOK * (3 * DIM);
    const ushort* Qg = qkv + base + h * HD;
    const ushort* Kg = qkv + base + DIM + h * HD;
    const ushort* Vg = qkv + base + 2 * DIM + h * HD;

    for (int chunk = tid; chunk < NTOK * 8; chunk += 256) {
        int r = chunk >> 3, c = (chunk & 7) * 8;
        uint4 v = *(const uint4*)(Kg + (size_t)r * (3 * DIM) + c);
        *(uint4*)&lds[KS_OFF + r * KS_STRIDE + c] = v;
    }
    for (int chunk = tid; chunk < 208 * 8; chunk += 256) {
        int k = chunk >> 3, c = (chunk & 7) * 8;
        uint4 v = {0u, 0u, 0u, 0u};
        if (k < NTOK) v = *(const uint4*)(Vg + (size_t)k * (3 * DIM) + c);
        const ushort* e = (const ushort*)&v;
        #pragma unroll
        for (int j = 0; j < 8; ++j) lds[VT_OFF + (c + j) * VT_STRIDE + k] = e[j];
    }
    __syncthreads();

    ushort* P = &lds[P_OFF + wid * 16 * P_STRIDE];

    for (int qi = wid; qi < 13; qi += 4) {
        int qrow = qi * 16 + fr; if (qrow > NTOK - 1) qrow = NTOK - 1;
        bf16x8 qf0 = *(const bf16x8*)(Qg + (size_t)qrow * (3 * DIM) + fq * 8);
        bf16x8 qf1 = *(const bf16x8*)(Qg + (size_t)qrow * (3 * DIM) + 32 + fq * 8);

        f32x4 sacc[13];
        #pragma unroll
        for (int t = 0; t < 13; ++t) {
            bf16x8 kf0 = *(const bf16x8*)&lds[KS_OFF + (t * 16 + fr) * KS_STRIDE + fq * 8];
            bf16x8 kf1 = *(const bf16x8*)&lds[KS_OFF + (t * 16 + fr) * KS_STRIDE + 32 + fq * 8];
            f32x4 z = {0.f, 0.f, 0.f, 0.f};
            z = MFMA16(kf0, qf0, z);
            sacc[t] = MFMA16(kf1, qf1, z);
        }

        float m = -1e30f;
        #pragma unroll
        for (int t = 0; t < 13; ++t)
            #pragma unroll
            for (int e = 0; e < 4; ++e) {
                int k = t * 16 + fq * 4 + e;
                float v = (k < NTOK) ? sacc[t][e] * 0.125f : -1e30f;
                sacc[t][e] = v;
                m = fmaxf(m, v);
            }
        m = fmaxf(m, __shfl_xor(m, 16));
        m = fmaxf(m, __shfl_xor(m, 32));
        float sum = 0.f;
        #pragma unroll
        for (int t = 0; t < 13; ++t)
            #pragma unroll
            for (int e = 0; e < 4; ++e) {
                float p = expf(sacc[t][e] - m);
                sacc[t][e] = p;
                sum += p;
            }
        sum += __shfl_xor(sum, 16);
        sum += __shfl_xor(sum, 32);
        float rd = 1.f / sum;

        #pragma unroll
        for (int t = 0; t < 13; ++t) {
            ushort2 w0 = { f2bf(sacc[t][0] * rd), f2bf(sacc[t][1] * rd) };
            ushort2 w1 = { f2bf(sacc[t][2] * rd), f2bf(sacc[t][3] * rd) };
            *(ushort2*)&P[fr * P_STRIDE + t * 16 + fq * 4]     = w0;
            *(ushort2*)&P[fr * P_STRIDE + t * 16 + fq * 4 + 2] = w1;
        }

        f32x4 oacc[4] = {};
        #pragma unroll
        for (int st = 0; st < 6; ++st) {
            bf16x8 pf = *(const bf16x8*)&P[fr * P_STRIDE + st * 32 + fq * 8];
            #pragma unroll
            for (int dt = 0; dt < 4; ++dt) {
                bf16x8 vf = *(const bf16x8*)&lds[VT_OFF + (dt * 16 + fr) * VT_STRIDE + st * 32 + fq * 8];
                oacc[dt] = MFMA16(pf, vf, oacc[dt]);
            }
        }
        {
            bf16x8 zz = {};
            bf16x8 pf = zz;
            if (fq < 2) pf = *(const bf16x8*)&P[fr * P_STRIDE + 192 + fq * 8];
            #pragma unroll
            for (int dt = 0; dt < 4; ++dt) {
                bf16x8 vf = zz;
                if (fq < 2) vf = *(const bf16x8*)&lds[VT_OFF + (dt * 16 + fr) * VT_STRIDE + 192 + fq * 8];
                oacc[dt] = MFMA16(pf, vf, oacc[dt]);
            }
        }

        #pragma unroll
        for (int dt = 0; dt < 4; ++dt)
            #pragma unroll
            for (int e = 0; e < 4; ++e) {
                int q = qi * 16 + fq * 4 + e;
                if (q < NTOK)
                    O[(size_t)(s * NTOK + q) * DIM + h * HD + dt * 16 + fr] = f2bf(oacc[dt][e]);
            }
    }
}

// ---------------------------------------------------------------------------
extern "C" void kernel_launch(void* const* d_in, const int* in_sizes, int n_in,
                              void* d_out, int out_size, void* d_ws, size_t ws_size,
                              hipStream_t stream)
{
    const float* x      = (const float*)d_in[0];
    const float* ln1_g  = (const float*)d_in[1];
    const float* ln1_b  = (const float*)d_in[2];
    const float* qkv_w  = (const float*)d_in[3];
    const float* proj_w = (const float*)d_in[4];
    const float* proj_b = (const float*)d_in[5];
    const float* tln_g  = (const float*)d_in[6];
    const float* tln_b  = (const float*)d_in[7];
    const float* tqkv_w = (const float*)d_in[8];
    const float* tproj_w= (const float*)d_in[9];
    const float* tproj_b= (const float*)d_in[10];
    const float* tfc_w  = (const float*)d_in[11];
    const float* tfc_b  = (const float*)d_in[12];
    const float* ln2_g  = (const float*)d_in[13];
    const float* ln2_b  = (const float*)d_in[14];
    const float* fc1_w  = (const float*)d_in[15];
    const float* fc1_b  = (const float*)d_in[16];
    const float* fc2_w  = (const float*)d_in[17];
    const float* fc2_b  = (const float*)d_in[18];

    float* out = (float*)d_out;   // fp32 residual accumulator = final output

    char* p = (char*)d_ws;
    ushort* w_qkv  = (ushort*)p; p += (size_t)(3*DIM*DIM) * 2;
    ushort* w_proj = (ushort*)p; p += (size_t)(DIM*DIM) * 2;
    ushort* w_tqkv = (ushort*)p; p += (size_t)(3*DIM*DIM) * 2;
    ushort* w_tfc  = (ushort*)p; p += (size_t)(DIM*DIM) * 2;
    ushort* tprojT = (ushort*)p; p += (size_t)(DIM*DIM) * 2;
    ushort* w_comb = (ushort*)p; p += (size_t)(DIM*DIM) * 2;
    ushort* w_fc1p = (ushort*)p; p += (size_t)(HIDP*DIM) * 2;
    ushort* w_fc2p = (ushort*)p; p += (size_t)(DIM*HIDP) * 2;
    float*  b_comb = (float*)p;  p += DIM * 4;
    float*  fc1_bp = (float*)p;  p += HIDP * 4;
    ushort* bufA   = (ushort*)p; p += (size_t)MROWS * DIM * 2;
    ushort* bufC   = (ushort*)p; p += (size_t)MROWS * DIM * 2;
    ushort* bufB   = (ushort*)p;  // MROWS*3*DIM bf16 (also holds [MROWS][1280])

    // ---- prep: casts / transposes / composition inputs ----
    {
        const int DD8 = DIM * DIM / 8;
        int c0 = 3 * DD8;                 // qkv
        int c1 = c0 + DD8;                // proj
        int c2 = c1 + 3 * DD8;            // tqkv
        int c3 = c2 + DD8;                // tfc
        int c4 = c3 + HID * DIM / 8;      // fc1 (into w_fc1p rows 0..1151)
        cast_all<<<dim3((c4 + 255) / 256), dim3(256), 0, stream>>>(
            qkv_w, w_qkv, c0, proj_w, w_proj, c1, tqkv_w, w_tqkv, c2,
            tfc_w, w_tfc, c3, fc1_w, w_fc1p, c4);
    }
    hipMemsetAsync(w_fc1p + (size_t)HID * DIM, 0, (size_t)(HIDP - HID) * DIM * 2, stream);
    transpose_cast<<<dim3(576), dim3(256), 0, stream>>>(tproj_w, tprojT);
    cast_pad_fc2<<<dim3((DIM * (HIDP / 8) + 255) / 256), dim3(256), 0, stream>>>(fc2_w, w_fc2p);
    pad_bias<<<dim3((HIDP + 255) / 256), dim3(256), 0, stream>>>(fc1_b, fc1_bp);
    bias_comb<<<dim3(DIM / 4), dim3(256), 0, stream>>>(tfc_w, tproj_b, tfc_b, b_comb);
    init_cls<<<dim3(48), dim3(256), 0, stream>>>(x, out);

    #define GEMM256(KV, EPI, A, W, BIAS, C, XS, XF, M, N, GRP) \
        gemm256<KV, EPI><<<dim3((((M) + 255) / 256) * ((N) / 256)), dim3(512), 0, stream>>>( \
            A, W, BIAS, C, XS, XF, M, N, ((M) + 255) / 256, (N) / 256, GRP)

    // W_comb = tfc @ tproj  (bf16, 768x768)
    GEMM256(DIM, EPI_STORE, w_tfc, tprojT, nullptr, w_comb, nullptr, nullptr, DIM, DIM, 1);

    // ---- temporal branch ----
    ln_gather<<<dim3(TROWS / 4), dim3(256), 0, stream>>>(x, tln_g, tln_b, bufA, TROWS);
    GEMM256(DIM, EPI_STORE, bufA, w_tqkv, nullptr, bufB, nullptr, nullptr, TROWS, 3 * DIM, 1);
    attn_temporal<<<dim3(TROWS * NH / 8 / 4), dim3(256), 0, stream>>>(bufB, bufC);
    GEMM256(DIM, EPI_INIT_TFC, bufC, w_comb, b_comb, nullptr, x, out, TROWS, DIM, 1);

    // ---- spatial attention ----
    ln_f32<<<dim3((MROWS + 3) / 4), dim3(256), 0, stream>>>(out, ln1_g, ln1_b, bufA, MROWS);
    GEMM256(DIM, EPI_STORE, bufA, w_qkv, nullptr, bufB, nullptr, nullptr, MROWS, 3 * DIM, 1);
    attn_spatial_mfma<<<dim3(BT_ * NH), dim3(256), 0, stream>>>(bufB, bufC);
    GEMM256(DIM, EPI_BIAS_ADD, bufC, w_proj, proj_b, nullptr, nullptr, out, MROWS, DIM, 1);

    // ---- MLP (padded HID' = 1280) ----
    ln_f32<<<dim3((MROWS + 3) / 4), dim3(256), 0, stream>>>(out, ln2_g, ln2_b, bufA, MROWS);
    GEMM256(DIM, EPI_BIAS_GELU, bufA, w_fc1p, fc1_bp, bufB, nullptr, nullptr, MROWS, HIDP, 1);
    GEMM256(HIDP, EPI_BIAS_ADD, bufB, w_fc2p, fc2_b, nullptr, nullptr, out, MROWS, DIM, 1);
    #undef GEMM256
}